// Round 9
// baseline (584.785 us; speedup 1.0000x reference)
//
#include <hip/hip_runtime.h>
#include <math.h>

#define PI_F 3.14159274101257324f   // float(np.pi)
#define TWO_PI_256 0.02454369260617026f   // 2*pi/256
#define TWO_PI_16  0.39269908169872414f   // 2*pi/16

typedef __attribute__((ext_vector_type(8))) short bf16x8;   // 4 VGPRs
typedef __attribute__((ext_vector_type(4))) float f32x4;

// ---------------- workspace layout (float offsets) ----------------
static const size_t OFF_FC    = 0;                    // row-FFT complex out [B*C*256][129]*2
static const size_t OFF_MLOG  = 3170304;              // [B,C,256,129]  (j-major: staging-coalesced)
static const size_t OFF_PH    = 4755456;              // [B,C,256,129]
static const size_t OFF_RSUM  = 9486336;              // [B,C,32]
static const size_t OFF_RCNT  = OFF_RSUM + 1536;      // [32]
static const size_t OFF_AS1   = OFF_RCNT + 32;        // [B,C,8]
static const size_t OFF_AS2   = OFF_AS1 + 384;        // [B,C,8]
static const size_t OFF_ACNT  = OFF_AS2 + 384;        // [8]
static const size_t OFF_MPOOL = OFF_ACNT + 8;         // [B,64]
static const size_t OFF_PPOOL = OFF_MPOOL + 1024;     // [B,32]
static const size_t OFF_RF    = OFF_PPOOL + 512;      // (unused)
static const size_t OFF_PAR   = OFF_RF + 512;         // 512 folded BN params
static const size_t OFF_WBM   = OFF_PAR + 512;        // mag conv2 w [9][64][64] bf16
static const size_t OFF_WBP   = OFF_WBM + 18432;      // ph conv2 w [9][32][32] bf16
static const size_t OFF_W1BM  = OFF_WBP + 4608;       // mag conv1 w [64][32] bf16
static const size_t OFF_W1BP  = OFF_W1BM + 1024;      // ph conv1 w [32][32] bf16
// param sub-offsets: sm1 0, tm1 64, sm2 128, tm2 192, sp1 256, tp1 288, sp2 320, tp2 352,
//                    sr1 384, tr1 416, sr2 448, tr2 480

__device__ __forceinline__ float fix_nan(float v, float pinf, float ninf) {
  if (isnan(v)) return 0.f;
  if (isinf(v)) return v > 0.f ? pinf : ninf;
  return v;
}

__device__ __forceinline__ unsigned short f2bf(float f) {
  unsigned u = __float_as_uint(f);
  unsigned r = (u + 0x7FFFu + ((u >> 16) & 1u)) >> 16;   // RNE (finite values only)
  return (unsigned short)r;
}

__device__ __forceinline__ void fold_bn(const float* bn, int C, int c, float cb,
                                        float* s, float* t) {
  float g = bn[c], b = bn[C + c], m = bn[2 * C + c], v = bn[3 * C + c];
  float sc = g / sqrtf(v + 1e-5f);
  *s = sc;
  *t = b + (cb - m) * sc;
}

// ---------------- row rFFT (radix-16) + fused prep + ws zeroing ----------------
__global__ __launch_bounds__(256) void row_fft_prep(
    const float* __restrict__ x, float* __restrict__ Fc, float* __restrict__ zbuf,
    const float* __restrict__ mw1, const float* __restrict__ pw1,
    const float* __restrict__ mw2, const float* __restrict__ pw2,
    const float* __restrict__ mb1, const float* __restrict__ mbn1,
    const float* __restrict__ mb2, const float* __restrict__ mbn2,
    const float* __restrict__ pb1, const float* __restrict__ pbn1,
    const float* __restrict__ pb2, const float* __restrict__ pbn2,
    const float* __restrict__ rb1, const float* __restrict__ rbn1,
    const float* __restrict__ rb2, const float* __restrict__ rbn2,
    float* __restrict__ par, unsigned short* __restrict__ wbm,
    unsigned short* __restrict__ wbp, unsigned short* __restrict__ w1bm,
    unsigned short* __restrict__ w1bp) {
  const int blk = blockIdx.x;
  const int tid = threadIdx.x;
  if (blk >= 12288) {
    int idx = (blk - 12288) * 256 + tid;
    if (idx < 36864) {
      int pos = idx / 4096, rem = idx % 4096;
      int oc = rem >> 6, ci = rem & 63;
      wbm[idx] = f2bf(mw2[(oc * 64 + ci) * 9 + pos]);
    } else if (idx < 46080) {
      int i = idx - 36864;
      int pos = i / 1024, rem = i % 1024;
      int oc = rem >> 5, ci = rem & 31;
      wbp[i] = f2bf(pw2[(oc * 32 + ci) * 9 + pos]);
    } else if (idx < 46336) {
      int i = idx - 46080;  // 0..255
      float s, t;
      if (i < 64)       { fold_bn(mbn1, 64, i, mb1[i], &s, &t);          par[i] = s;       par[64 + i] = t; }
      else if (i < 128) { int c = i - 64;  fold_bn(mbn2, 64, c, mb2[c], &s, &t); par[128 + c] = s; par[192 + c] = t; }
      else if (i < 160) { int c = i - 128; fold_bn(pbn1, 32, c, pb1[c], &s, &t); par[256 + c] = s; par[288 + c] = t; }
      else if (i < 192) { int c = i - 160; fold_bn(pbn2, 32, c, pb2[c], &s, &t); par[320 + c] = s; par[352 + c] = t; }
      else if (i < 224) { int c = i - 192; fold_bn(rbn1, 32, c, rb1[c], &s, &t); par[384 + c] = s; par[416 + c] = t; }
      else              { int c = i - 224; fold_bn(rbn2, 32, c, rb2[c], &s, &t); par[448 + c] = s; par[480 + c] = t; }
    } else if (idx < 48384) {
      int i = idx - 46336;                 // conv1 mag w [oc][k], k=c*9+dy*3+dx, pad->0
      int oc = i >> 5, k = i & 31;
      w1bm[i] = (k < 27) ? f2bf(mw1[oc * 27 + k]) : (unsigned short)0;
    } else if (idx < 49408) {
      int i = idx - 48384;
      int oc = i >> 5, k = i & 31;
      w1bp[i] = (k < 27) ? f2bf(pw1[oc * 27 + k]) : (unsigned short)0;
    }
    return;
  }
  if (blk == 0) {
    for (int i = tid; i < 3880; i += 256) zbuf[i] = 0.f;   // rsum..ppool accumulators
  }
  __shared__ float xr[256];
  __shared__ float2 sS[256];
  {
    float v = x[(size_t)blk * 256 + tid];
    xr[tid] = fminf(fmaxf(v, -10.f), 10.f);
  }
  __syncthreads();
  // stage 1: real-input 16-pt DFTs over strided subsequences
  {
    int b16 = tid >> 4, m = tid & 15;
    float sW, cW;
    sincosf(TWO_PI_16 * (float)m, &sW, &cW);   // W = e^{-i 2pi m/16} = (cW, -sW)
    float sr = 0.f, si = 0.f, wr = 1.f, wi = 0.f;
#pragma unroll
    for (int a = 0; a < 16; ++a) {
      float xv = xr[a * 16 + b16];
      sr = fmaf(xv, wr, sr);
      si = fmaf(xv, wi, si);
      float nr = wr * cW + wi * sW;
      float ni = wi * cW - wr * sW;
      wr = nr; wi = ni;
    }
    sS[b16 * 16 + m] = make_float2(sr, si);
  }
  __syncthreads();
  // stage 2: combine with W256^{kb}
  if (tid < 129) {
    int m2 = tid & 15;
    float sK, cK;
    sincosf(TWO_PI_256 * (float)tid, &sK, &cK);  // e^{-i 2pi k/256} = (cK, -sK)
    float fr = 0.f, fi = 0.f, wr = 1.f, wi = 0.f;
#pragma unroll
    for (int bb = 0; bb < 16; ++bb) {
      float2 s = sS[bb * 16 + m2];
      fr = fmaf(s.x, wr, fr); fr = fmaf(-s.y, wi, fr);
      fi = fmaf(s.x, wi, fi); fi = fmaf(s.y, wr, fi);
      float nr = wr * cK + wi * sK;
      float ni = wi * cK - wr * sK;
      wr = nr; wi = ni;
    }
    float2* o = (float2*)Fc;
    o[(size_t)blk * 129 + tid] = make_float2(fr, fi);
  }
}

// ---------------- column DFT (radix-16, 3 channels/block) + stats ----------------
__global__ __launch_bounds__(256) void col_fft_stats(
    const float* __restrict__ Fc, float* __restrict__ mlog, float* __restrict__ ph,
    float* __restrict__ rsum, float* __restrict__ rcnt, float* __restrict__ as1,
    float* __restrict__ as2, float* __restrict__ acnt) {
  const int k = blockIdx.x, b = blockIdx.y;
  const int tid = threadIdx.x;
  const int cp = tid >> 7;          // 2 histogram copies
  __shared__ float2 col[3][256];
  __shared__ float2 sS[3][256];
  __shared__ float l_rs[3][2][32];
  __shared__ float l_rc[32];
  __shared__ float l_s1[3][2][8], l_s2[3][2][8];
  __shared__ float l_ac[8];
  for (int i = tid; i < 192; i += 256) {
    int c = i / 64, r = i % 64;
    l_rs[c][r >> 5][r & 31] = 0.f;
  }
  if (tid < 32) l_rc[tid] = 0.f;
  if (tid < 48) { int c = tid / 16, r = tid % 16; l_s1[c][r >> 3][r & 7] = 0.f; l_s2[c][r >> 3][r & 7] = 0.f; }
  if (tid < 8) l_ac[tid] = 0.f;
  const float2* fc = (const float2*)Fc;
#pragma unroll
  for (int c = 0; c < 3; ++c)
    col[c][tid] = fc[((size_t)((b * 3 + c) * 256) + tid) * 129 + k];
  __syncthreads();
  // stage 1 (complex input)
  {
    int b16 = tid >> 4, m = tid & 15;
    float sW, cW;
    sincosf(TWO_PI_16 * (float)m, &sW, &cW);
#pragma unroll
    for (int c = 0; c < 3; ++c) {
      float sr = 0.f, si = 0.f, wr = 1.f, wi = 0.f;
#pragma unroll
      for (int a = 0; a < 16; ++a) {
        float2 v = col[c][a * 16 + b16];
        sr = fmaf(v.x, wr, sr); sr = fmaf(-v.y, wi, sr);
        si = fmaf(v.x, wi, si); si = fmaf(v.y, wr, si);
        float nr = wr * cW + wi * sW;
        float ni = wi * cW - wr * sW;
        wr = nr; wi = ni;
      }
      sS[c][b16 * 16 + m] = make_float2(sr, si);
    }
  }
  __syncthreads();
  const int j = tid;
  float sK, cK;
  sincosf(TWO_PI_256 * (float)j, &sK, &cK);
  float gr[3], gi[3];
#pragma unroll
  for (int c = 0; c < 3; ++c) {
    float fr = 0.f, fi = 0.f, wr = 1.f, wi = 0.f;
#pragma unroll
    for (int bb = 0; bb < 16; ++bb) {
      float2 s = sS[c][bb * 16 + (j & 15)];
      fr = fmaf(s.x, wr, fr); fr = fmaf(-s.y, wi, fr);
      fi = fmaf(s.x, wi, fi); fi = fmaf(s.y, wr, fi);
      float nr = wr * cK + wi * sK;
      float ni = wi * cK - wr * sK;
      wr = nr; wi = ni;
    }
    gr[c] = fr; gi[c] = fi;
  }
  // bins once per (j,k) (bit-exact fp32 replication of reference index math)
  float fy = (float)(j < 128 ? j : j - 256) * (1.0f / 256.0f);
  float fx = (float)k * (1.0f / 256.0f);
  float rad = sqrtf(fx * fx + fy * fy);
  float denom = sqrtf(0.5f) + 1e-8f;
  int rb = (int)((rad / denom) * 31.0f);
  rb = rb < 0 ? 0 : (rb > 31 ? 31 : rb);
  float ang = atan2f(fy, fx + 1e-8f);
  int ab = (int)((ang + PI_F) / (2.0f * PI_F) * 8.0f);
  ab = ab < 0 ? 0 : (ab > 7 ? 7 : ab);
#pragma unroll
  for (int c = 0; c < 3; ++c) {
    float mag = sqrtf(gr[c] * gr[c] + gi[c] * gi[c]);
    mag = fminf(fmaxf(mag, 1e-8f), 1e6f);
    float ml = fminf(fmaxf(log1pf(mag), -20.f), 20.f);
    float p = fminf(fmaxf(atan2f(gi[c], gr[c]) / PI_F, -1.f), 1.f);
    size_t oidx = ((size_t)((b * 3 + c) * 256) + j) * 129 + k;   // j-major
    mlog[oidx] = ml;
    ph[oidx] = p;
    atomicAdd(&l_rs[c][cp][rb], mag);
    atomicAdd(&l_s1[c][cp][ab], mag);
    atomicAdd(&l_s2[c][cp][ab], mag * mag);
  }
  if (b == 0) {
    atomicAdd(&l_rc[rb], 1.0f);
    atomicAdd(&l_ac[ab], 1.0f);
  }
  __syncthreads();
  if (tid < 96) {
    int c = tid / 32, i2 = tid % 32;
    atomicAdd(&rsum[(b * 3 + c) * 32 + i2], l_rs[c][0][i2] + l_rs[c][1][i2]);
  } else if (tid < 120) {
    int t2 = tid - 96;
    int c = t2 / 8, a2 = t2 % 8;
    atomicAdd(&as1[(b * 3 + c) * 8 + a2], l_s1[c][0][a2] + l_s1[c][1][a2]);
    atomicAdd(&as2[(b * 3 + c) * 8 + a2], l_s2[c][0][a2] + l_s2[c][1][a2]);
  }
  if (b == 0) {
    if (tid < 32) atomicAdd(&rcnt[tid], l_rc[tid]);
    else if (tid < 40) atomicAdd(&acnt[tid - 32], l_ac[tid - 32]);
  }
}

// ---------------- fused upsample -> conv1(MFMA) -> conv2(MFMA) -> pool ----------------
// SEPARATE dispatches per branch (round-8 postmortem: merging both template bodies
// into one kernel caused scratch spill -> 1.1 GB HBM traffic). K-split (f1 = 32 ci
// at a time, LDS ~31 KB) + rolling register B prefetch over (hf,kx) granules.
template <int C2>
__device__ __forceinline__ void conv_impl(
    const float* __restrict__ src,           // [B,3,256,129] spectral plane (j-major)
    const unsigned short* __restrict__ w1b,  // [C2][32] bf16 conv1 weights
    const unsigned short* __restrict__ wB,   // [9][C2][C2] bf16 conv2 [pos][oc][ci]
    const float* __restrict__ s1, const float* __restrict__ t1,
    const float* __restrict__ s2, const float* __restrict__ t2,
    float* __restrict__ pool, int b, int tx0, int ty0, int tid,
    float (&s_in)[3][20][20], float* s_sc1, float* s_sh1, unsigned short* s_f1) {
  constexpr int HALVES = C2 / 32;
  constexpr int ST = 40;                     // 32 ci + 8 pad (rows 80 B, 16B-aligned)
  constexpr int WNT = C2 / 32;               // conv2 oc tiles per wave (2 or 1)
  constexpr int G = HALVES * 3;              // (hf,kx) granules

  const int lane = tid & 63, wv = tid >> 6;
  const int ln = lane & 15, q = lane >> 4;
  const int ntg = wv & 1, half_w = wv >> 1;
  const int ocb0 = ntg * WNT * 16;

  // stage input tile (halo 2) with fused bilinear W-upsample (129 -> 256);
  // j-major src: row base (b*3+c)*256+gy, consecutive x0 -> coalesced
  for (int idx = tid; idx < 1200; idx += 256) {
    int c = idx / 400, r = idx % 400, iy = r / 20, ix = r % 20;
    int gy = ty0 - 2 + iy, gx = tx0 - 2 + ix;
    float v = 0.f;
    if ((unsigned)gy < 256u && (unsigned)gx < 256u) {
      float srcx = ((float)gx + 0.5f) * (129.0f / 256.0f) - 0.5f;
      float fl = floorf(srcx);
      float w = srcx - fl;
      int x0 = (int)fl, x1 = x0 + 1;
      x0 = x0 < 0 ? 0 : x0;
      x1 = x1 > 128 ? 128 : x1;
      const float* rowp = src + ((size_t)(b * 3 + c) * 256 + gy) * 129;
      v = rowp[x0] * (1.f - w) + rowp[x1] * w;
    }
    s_in[c][iy][ix] = v;
  }
  if (tid < C2) { s_sc1[tid] = s1[tid]; s_sh1[tid] = t1[tid]; }

  // rolling conv2 B prefetch: granule 0 issued before the barrier
  bf16x8 Bb[2][WNT * 3];
#pragma unroll
  for (int w = 0; w < WNT; ++w)
#pragma unroll
    for (int ky = 0; ky < 3; ++ky)
      Bb[0][w * 3 + ky] =
          *(const bf16x8*)&wB[((size_t)(ky * 3 + 0) * C2 + ocb0 + w * 16 + ln) * C2 + 0 + q * 8];

  __syncthreads();

  // per-lane conv1 gather offsets (k = c*9 + dy*3 + dx)
  const float* sp = &s_in[0][0][0];
  int koff[8];
#pragma unroll
  for (int j = 0; j < 8; ++j) {
    int k = q * 8 + j;
    if (k < 27) {
      int c = k / 9, rr = k - c * 9, dy = rr / 3, dx = rr - dy * 3;
      koff[j] = (c * 20 + dy) * 20 + dx;
    } else koff[j] = -1;
  }

  f32x4 acc[WNT][8];
#pragma unroll
  for (int w = 0; w < WNT; ++w)
#pragma unroll
    for (int i = 0; i < 8; ++i)
      acc[w][i] = (f32x4){0.f, 0.f, 0.f, 0.f};

  const int rbase = half_w * 8;

#pragma unroll
  for (int hf = 0; hf < HALVES; ++hf) {
    if (hf > 0) __syncthreads();   // conv2(hf-1) readers done before overwrite
    // conv1 weights + BN params for this half's 32 oc
    bf16x8 b1h[2];
    float c1sc[2][4], c1sh[2][4];
#pragma unroll
    for (int w = 0; w < 2; ++w) {
      int nt = hf * 2 + w;
      b1h[w] = *(const bf16x8*)&w1b[(nt * 16 + ln) * 32 + q * 8];
#pragma unroll
      for (int r = 0; r < 4; ++r) {
        c1sc[w][r] = s_sc1[hf * 32 + w * 16 + q * 4 + r];
        c1sh[w][r] = s_sh1[hf * 32 + w * 16 + q * 4 + r];
      }
    }
    // ---- conv1: D[oc][pixel], 21 pixel-tiles of 16 over the 18x18 halo ----
    for (int mt = wv; mt < 21; mt += 4) {
      int p = mt * 16 + ln;
      int pc = p < 324 ? p : 0;
      int py = pc / 18, px = pc - py * 18;
      int pix = py * 20 + px;
      union { bf16x8 v; unsigned u[4]; } af;
#pragma unroll
      for (int jj = 0; jj < 4; ++jj) {
        float v0 = (koff[2 * jj] >= 0) ? sp[koff[2 * jj] + pix] : 0.f;
        float v1 = (koff[2 * jj + 1] >= 0) ? sp[koff[2 * jj + 1] + pix] : 0.f;
        af.u[jj] = (unsigned)f2bf(v0) | ((unsigned)f2bf(v1) << 16);
      }
      bool inim = false;
      if (p < 324) {
        int gy = ty0 - 1 + py, gx = tx0 - 1 + px;
        inim = ((unsigned)gy < 256u) && ((unsigned)gx < 256u);
      }
#pragma unroll
      for (int w = 0; w < 2; ++w) {
        f32x4 c1 = __builtin_amdgcn_mfma_f32_16x16x32_bf16(
            b1h[w], af.v, (f32x4){0.f, 0.f, 0.f, 0.f}, 0, 0, 0);
        if (p < 324) {
          float v0 = inim ? fmaxf(fmaf(c1[0], c1sc[w][0], c1sh[w][0]), 0.f) : 0.f;
          float v1 = inim ? fmaxf(fmaf(c1[1], c1sc[w][1], c1sh[w][1]), 0.f) : 0.f;
          float v2 = inim ? fmaxf(fmaf(c1[2], c1sc[w][2], c1sh[w][2]), 0.f) : 0.f;
          float v3 = inim ? fmaxf(fmaf(c1[3], c1sc[w][3], c1sh[w][3]), 0.f) : 0.f;
          uint2 pk;
          pk.x = (unsigned)f2bf(v0) | ((unsigned)f2bf(v1) << 16);
          pk.y = (unsigned)f2bf(v2) | ((unsigned)f2bf(v3) << 16);
          *(uint2*)&s_f1[p * ST + w * 16 + q * 4] = pk;
        }
      }
    }
    __syncthreads();
    // ---- conv2: 3 kx granules over this half's 32 ci, rolling B prefetch ----
#pragma unroll
    for (int kx = 0; kx < 3; ++kx) {
      const int g = hf * 3 + kx;
      if (g + 1 < G) {
        const int nhf = (g + 1) / 3, nkx = (g + 1) % 3;
#pragma unroll
        for (int w = 0; w < WNT; ++w)
#pragma unroll
          for (int ky = 0; ky < 3; ++ky)
            Bb[(g + 1) & 1][w * 3 + ky] =
                *(const bf16x8*)&wB[((size_t)(ky * 3 + nkx) * C2 + ocb0 + w * 16 + ln) * C2 +
                                    nhf * 32 + q * 8];
      }
      bf16x8 a[10];
#pragma unroll
      for (int rr = 0; rr < 10; ++rr)
        a[rr] = *(const bf16x8*)&s_f1[((rbase + rr) * 18 + ln + kx) * ST + q * 8];
#pragma unroll
      for (int ky = 0; ky < 3; ++ky)
#pragma unroll
        for (int w = 0; w < WNT; ++w)
#pragma unroll
          for (int i = 0; i < 8; ++i)
            acc[w][i] = __builtin_amdgcn_mfma_f32_16x16x32_bf16(a[i + ky], Bb[g & 1][w * 3 + ky],
                                                                acc[w][i], 0, 0, 0);
    }
  }

  // epilogue: BN+ReLU + pool partial. D: col(ln)=oc, rows=pixel cols (q*4+r).
#pragma unroll
  for (int w = 0; w < WNT; ++w) {
    const int oc = ocb0 + w * 16 + ln;
    const float sc = s2[oc], sh = t2[oc];
    float v = 0.f;
#pragma unroll
    for (int i = 0; i < 8; ++i)
#pragma unroll
      for (int r = 0; r < 4; ++r)
        v += fmaxf(fmaf(acc[w][i][r], sc, sh), 0.f);
    v += __shfl_xor(v, 16);
    v += __shfl_xor(v, 32);
    if (q == 0) atomicAdd(&pool[b * C2 + oc], v);
  }
}

// Separate __global__ wrappers (one template body each -> no spill).
__global__ __launch_bounds__(256, 3) void conv_mag(
    const float* __restrict__ src, const unsigned short* __restrict__ w1b,
    const unsigned short* __restrict__ wB, const float* __restrict__ par,
    float* __restrict__ pool) {
  __shared__ float s_in[3][20][20];
  __shared__ float s_sc1[64], s_sh1[64];
  __shared__ __align__(16) unsigned short s_f1[324 * 40];
  conv_impl<64>(src, w1b, wB, par + 0, par + 64, par + 128, par + 192, pool,
                blockIdx.z, blockIdx.x * 16, blockIdx.y * 16, threadIdx.x,
                s_in, s_sc1, s_sh1, s_f1);
}

__global__ __launch_bounds__(256, 3) void conv_ph(
    const float* __restrict__ src, const unsigned short* __restrict__ w1b,
    const unsigned short* __restrict__ wB, const float* __restrict__ par,
    float* __restrict__ pool) {
  __shared__ float s_in[3][20][20];
  __shared__ float s_sc1[64], s_sh1[64];
  __shared__ __align__(16) unsigned short s_f1[324 * 40];
  conv_impl<32>(src, w1b, wB, par + 256, par + 288, par + 320, par + 352, pool,
                blockIdx.z, blockIdx.x * 16, blockIdx.y * 16, threadIdx.x,
                s_in, s_sc1, s_sh1, s_f1);
}

// ---------------- final: radial conv branch + comb + linear/LN/relu/linear ----------------
__global__ __launch_bounds__(256) void final_mlp(
    const float* __restrict__ rsum, const float* __restrict__ rcnt,
    const float* __restrict__ rw1, const float* __restrict__ rw2,
    const float* __restrict__ sr1, const float* __restrict__ tr1,
    const float* __restrict__ sr2, const float* __restrict__ tr2,
    const float* __restrict__ mpool, const float* __restrict__ ppool,
    const float* __restrict__ as1, const float* __restrict__ as2,
    const float* __restrict__ acnt,
    const float* __restrict__ lw1, const float* __restrict__ lb1,
    const float* __restrict__ lng, const float* __restrict__ lnb,
    const float* __restrict__ lw2, const float* __restrict__ lb2,
    float* __restrict__ out) {
  int b = blockIdx.x, t = threadIdx.x;
  __shared__ float rad[3][32];
  __shared__ float rf1[32][32];
  __shared__ float rf2[32][32];
  __shared__ float rfv[32];
  __shared__ float comb[176];
  __shared__ float red[256];
  __shared__ float hrelu[256];
  __shared__ float s_mu, s_var;

  if (t < 96) {
    int c = t / 32, i = t % 32;
    float cnt = fmaxf(rcnt[i], 1.0f);
    float v = rsum[(b * 3 + c) * 32 + i] / cnt;
    rad[c][i] = fminf(fmaxf(v, 0.f), 1e6f);
  }
  __syncthreads();
  for (int idx = t; idx < 1024; idx += 256) {
    int oc = idx >> 5, i = idx & 31;
    float a = 0.f;
    for (int c = 0; c < 3; ++c)
#pragma unroll
      for (int d = 0; d < 3; ++d) {
        int ii = i + d - 1;
        if (ii >= 0 && ii < 32) a = fmaf(rad[c][ii], rw1[(oc * 3 + c) * 3 + d], a);
      }
    rf1[oc][i] = fmaxf(fmaf(a, sr1[oc], tr1[oc]), 0.f);
  }
  __syncthreads();
  for (int idx = t; idx < 1024; idx += 256) {
    int oc = idx >> 5, i = idx & 31;
    float a = 0.f;
    for (int c = 0; c < 32; ++c)
#pragma unroll
      for (int d = 0; d < 3; ++d) {
        int ii = i + d - 1;
        if (ii >= 0 && ii < 32) a = fmaf(rf1[c][ii], rw2[(oc * 32 + c) * 3 + d], a);
      }
    rf2[oc][i] = fmaxf(fmaf(a, sr2[oc], tr2[oc]), 0.f);
  }
  __syncthreads();
  if (t < 32) {
    float s = 0.f;
    for (int i = 0; i < 32; ++i) s += rf2[t][i];
    rfv[t] = s * (1.0f / 32.0f);
  }
  __syncthreads();

  if (t < 64) comb[t] = fix_nan(mpool[b * 64 + t] * (1.0f / 65536.0f), 1e4f, -1e4f);
  else if (t < 96) comb[t] = fix_nan(ppool[b * 32 + t - 64] * (1.0f / 65536.0f), 1e4f, -1e4f);
  else if (t < 128) comb[t] = fix_nan(rfv[t - 96], 1e4f, -1e4f);
  else if (t < 176) {
    int j = t - 128;
    int a = j / 6, r = j % 6, m = r / 3, c = r % 3;
    float cnt = acnt[a];
    float v = 0.f;  // empty sector -> NaN -> nan_to_num -> 0
    if (cnt > 0.f) {
      float s1v = as1[(b * 3 + c) * 8 + a], s2v = as2[(b * 3 + c) * 8 + a];
      float mean = s1v / cnt;
      if (m == 0)
        v = mean;
      else {
        float var = (s2v - cnt * mean * mean) / fmaxf(cnt - 1.f, 1.f);
        v = sqrtf(fmaxf(var, 0.f));
      }
    }
    comb[t] = fix_nan(v, 1e4f, -1e4f);
  }
  __syncthreads();
  float h = lb1[t];
  const float* wr = lw1 + t * 176;
#pragma unroll 8
  for (int j = 0; j < 176; ++j) h = fmaf(comb[j], wr[j], h);
  red[t] = h;
  __syncthreads();
  for (int s = 128; s > 0; s >>= 1) {
    if (t < s) red[t] += red[t + s];
    __syncthreads();
  }
  if (t == 0) s_mu = red[0] * (1.0f / 256.0f);
  __syncthreads();
  float mu = s_mu;
  float d = h - mu;
  red[t] = d * d;
  __syncthreads();
  for (int s = 128; s > 0; s >>= 1) {
    if (t < s) red[t] += red[t + s];
    __syncthreads();
  }
  if (t == 0) s_var = red[0] * (1.0f / 256.0f);
  __syncthreads();
  float hn = d / sqrtf(s_var + 1e-5f) * lng[t] + lnb[t];
  hrelu[t] = fmaxf(hn, 0.f);
  __syncthreads();
  if (t < 128) {
    float o = lb2[t];
    const float* w2r = lw2 + t * 256;
#pragma unroll 8
    for (int j = 0; j < 256; ++j) o = fmaf(hrelu[j], w2r[j], o);
    o = fminf(fmaxf(o, -100.f), 100.f);
    out[b * 128 + t] = fix_nan(o, 100.f, -100.f);
  }
}

// ---------------- host launcher ----------------
extern "C" void kernel_launch(void* const* d_in, const int* in_sizes, int n_in,
                              void* d_out, int out_size, void* d_ws, size_t ws_size,
                              hipStream_t stream) {
  const float* x    = (const float*)d_in[0];
  const float* mw1  = (const float*)d_in[1];
  const float* mb1  = (const float*)d_in[2];
  const float* mbn1 = (const float*)d_in[3];
  const float* mw2  = (const float*)d_in[4];
  const float* mb2  = (const float*)d_in[5];
  const float* mbn2 = (const float*)d_in[6];
  const float* pw1  = (const float*)d_in[7];
  const float* pb1  = (const float*)d_in[8];
  const float* pbn1 = (const float*)d_in[9];
  const float* pw2  = (const float*)d_in[10];
  const float* pb2  = (const float*)d_in[11];
  const float* pbn2 = (const float*)d_in[12];
  const float* rw1  = (const float*)d_in[13];
  const float* rb1  = (const float*)d_in[14];
  const float* rbn1 = (const float*)d_in[15];
  const float* rw2  = (const float*)d_in[16];
  const float* rb2  = (const float*)d_in[17];
  const float* rbn2 = (const float*)d_in[18];
  const float* lw1  = (const float*)d_in[19];
  const float* lb1  = (const float*)d_in[20];
  const float* lng  = (const float*)d_in[21];
  const float* lnb  = (const float*)d_in[22];
  const float* lw2  = (const float*)d_in[23];
  const float* lb2  = (const float*)d_in[24];

  float* ws = (float*)d_ws;
  float* out = (float*)d_out;

  float* fc    = ws + OFF_FC;
  float* mlog  = ws + OFF_MLOG;
  float* phb   = ws + OFF_PH;
  float* rsum  = ws + OFF_RSUM;
  float* rcnt  = ws + OFF_RCNT;
  float* as1   = ws + OFF_AS1;
  float* as2   = ws + OFF_AS2;
  float* acnt  = ws + OFF_ACNT;
  float* mpool = ws + OFF_MPOOL;
  float* ppool = ws + OFF_PPOOL;
  float* par   = ws + OFF_PAR;
  unsigned short* wbm  = (unsigned short*)(ws + OFF_WBM);
  unsigned short* wbp  = (unsigned short*)(ws + OFF_WBP);
  unsigned short* w1bm = (unsigned short*)(ws + OFF_W1BM);
  unsigned short* w1bp = (unsigned short*)(ws + OFF_W1BP);

  row_fft_prep<<<12481, 256, 0, stream>>>(x, fc, rsum,
                                          mw1, pw1, mw2, pw2, mb1, mbn1, mb2, mbn2,
                                          pb1, pbn1, pb2, pbn2, rb1, rbn1, rb2, rbn2,
                                          par, wbm, wbp, w1bm, w1bp);
  col_fft_stats<<<dim3(129, 16), 256, 0, stream>>>(fc, mlog, phb, rsum, rcnt,
                                                   as1, as2, acnt);
  conv_mag<<<dim3(16, 16, 16), 256, 0, stream>>>(mlog, w1bm, wbm, par, mpool);
  conv_ph<<<dim3(16, 16, 16), 256, 0, stream>>>(phb, w1bp, wbp, par, ppool);
  final_mlp<<<16, 256, 0, stream>>>(rsum, rcnt, rw1, rw2, par + 384, par + 416,
                                    par + 448, par + 480, mpool, ppool, as1, as2,
                                    acnt, lw1, lb1, lng, lnb, lw2, lb2, out);
}

// Round 10
// 443.151 us; speedup vs baseline: 1.3196x; 1.3196x over previous
//
#include <hip/hip_runtime.h>
#include <math.h>

#define PI_F 3.14159274101257324f   // float(np.pi)
#define TWO_PI_256 0.02454369260617026f   // 2*pi/256
#define TWO_PI_16  0.39269908169872414f   // 2*pi/16

typedef __attribute__((ext_vector_type(8))) short bf16x8;   // 4 VGPRs
typedef __attribute__((ext_vector_type(4))) float f32x4;

// ---------------- workspace layout (float offsets) ----------------
static const size_t OFF_FC    = 0;                    // row-FFT complex out [B*C*256][129]*2
static const size_t OFF_MLOG  = 3170304;              // [B,C,256,129]  (j-major: staging-coalesced)
static const size_t OFF_PH    = 4755456;              // [B,C,256,129]
static const size_t OFF_RSUM  = 9486336;              // [B,C,32]
static const size_t OFF_RCNT  = OFF_RSUM + 1536;      // [32]
static const size_t OFF_AS1   = OFF_RCNT + 32;        // [B,C,8]
static const size_t OFF_AS2   = OFF_AS1 + 384;        // [B,C,8]
static const size_t OFF_ACNT  = OFF_AS2 + 384;        // [8]
static const size_t OFF_MPOOL = OFF_ACNT + 8;         // [B,64]
static const size_t OFF_PPOOL = OFF_MPOOL + 1024;     // [B,32]
static const size_t OFF_RF    = OFF_PPOOL + 512;      // (unused)
static const size_t OFF_PAR   = OFF_RF + 512;         // 512 folded BN params
static const size_t OFF_WBM   = OFF_PAR + 512;        // mag conv2 w [9][64][64] bf16
static const size_t OFF_WBP   = OFF_WBM + 18432;      // ph conv2 w [9][32][32] bf16
static const size_t OFF_W1BM  = OFF_WBP + 4608;       // mag conv1 w [64][32] bf16
static const size_t OFF_W1BP  = OFF_W1BM + 1024;      // ph conv1 w [32][32] bf16
// param sub-offsets: sm1 0, tm1 64, sm2 128, tm2 192, sp1 256, tp1 288, sp2 320, tp2 352,
//                    sr1 384, tr1 416, sr2 448, tr2 480

__device__ __forceinline__ float fix_nan(float v, float pinf, float ninf) {
  if (isnan(v)) return 0.f;
  if (isinf(v)) return v > 0.f ? pinf : ninf;
  return v;
}

__device__ __forceinline__ unsigned short f2bf(float f) {
  unsigned u = __float_as_uint(f);
  unsigned r = (u + 0x7FFFu + ((u >> 16) & 1u)) >> 16;   // RNE (finite values only)
  return (unsigned short)r;
}

__device__ __forceinline__ void fold_bn(const float* bn, int C, int c, float cb,
                                        float* s, float* t) {
  float g = bn[c], b = bn[C + c], m = bn[2 * C + c], v = bn[3 * C + c];
  float sc = g / sqrtf(v + 1e-5f);
  *s = sc;
  *t = b + (cb - m) * sc;
}

// ---------------- row rFFT (radix-16) + fused prep + ws zeroing ----------------
__global__ __launch_bounds__(256) void row_fft_prep(
    const float* __restrict__ x, float* __restrict__ Fc, float* __restrict__ zbuf,
    const float* __restrict__ mw1, const float* __restrict__ pw1,
    const float* __restrict__ mw2, const float* __restrict__ pw2,
    const float* __restrict__ mb1, const float* __restrict__ mbn1,
    const float* __restrict__ mb2, const float* __restrict__ mbn2,
    const float* __restrict__ pb1, const float* __restrict__ pbn1,
    const float* __restrict__ pb2, const float* __restrict__ pbn2,
    const float* __restrict__ rb1, const float* __restrict__ rbn1,
    const float* __restrict__ rb2, const float* __restrict__ rbn2,
    float* __restrict__ par, unsigned short* __restrict__ wbm,
    unsigned short* __restrict__ wbp, unsigned short* __restrict__ w1bm,
    unsigned short* __restrict__ w1bp) {
  const int blk = blockIdx.x;
  const int tid = threadIdx.x;
  if (blk >= 12288) {
    int idx = (blk - 12288) * 256 + tid;
    if (idx < 36864) {
      int pos = idx / 4096, rem = idx % 4096;
      int oc = rem >> 6, ci = rem & 63;
      wbm[idx] = f2bf(mw2[(oc * 64 + ci) * 9 + pos]);
    } else if (idx < 46080) {
      int i = idx - 36864;
      int pos = i / 1024, rem = i % 1024;
      int oc = rem >> 5, ci = rem & 31;
      wbp[i] = f2bf(pw2[(oc * 32 + ci) * 9 + pos]);
    } else if (idx < 46336) {
      int i = idx - 46080;  // 0..255
      float s, t;
      if (i < 64)       { fold_bn(mbn1, 64, i, mb1[i], &s, &t);          par[i] = s;       par[64 + i] = t; }
      else if (i < 128) { int c = i - 64;  fold_bn(mbn2, 64, c, mb2[c], &s, &t); par[128 + c] = s; par[192 + c] = t; }
      else if (i < 160) { int c = i - 128; fold_bn(pbn1, 32, c, pb1[c], &s, &t); par[256 + c] = s; par[288 + c] = t; }
      else if (i < 192) { int c = i - 160; fold_bn(pbn2, 32, c, pb2[c], &s, &t); par[320 + c] = s; par[352 + c] = t; }
      else if (i < 224) { int c = i - 192; fold_bn(rbn1, 32, c, rb1[c], &s, &t); par[384 + c] = s; par[416 + c] = t; }
      else              { int c = i - 224; fold_bn(rbn2, 32, c, rb2[c], &s, &t); par[448 + c] = s; par[480 + c] = t; }
    } else if (idx < 48384) {
      int i = idx - 46336;                 // conv1 mag w [oc][k], k=c*9+dy*3+dx, pad->0
      int oc = i >> 5, k = i & 31;
      w1bm[i] = (k < 27) ? f2bf(mw1[oc * 27 + k]) : (unsigned short)0;
    } else if (idx < 49408) {
      int i = idx - 48384;
      int oc = i >> 5, k = i & 31;
      w1bp[i] = (k < 27) ? f2bf(pw1[oc * 27 + k]) : (unsigned short)0;
    }
    return;
  }
  if (blk == 0) {
    for (int i = tid; i < 3880; i += 256) zbuf[i] = 0.f;   // rsum..ppool accumulators
  }
  __shared__ float xr[256];
  __shared__ float2 sS[256];
  {
    float v = x[(size_t)blk * 256 + tid];
    xr[tid] = fminf(fmaxf(v, -10.f), 10.f);
  }
  __syncthreads();
  // stage 1: real-input 16-pt DFTs over strided subsequences
  {
    int b16 = tid >> 4, m = tid & 15;
    float sW, cW;
    sincosf(TWO_PI_16 * (float)m, &sW, &cW);   // W = e^{-i 2pi m/16} = (cW, -sW)
    float sr = 0.f, si = 0.f, wr = 1.f, wi = 0.f;
#pragma unroll
    for (int a = 0; a < 16; ++a) {
      float xv = xr[a * 16 + b16];
      sr = fmaf(xv, wr, sr);
      si = fmaf(xv, wi, si);
      float nr = wr * cW + wi * sW;
      float ni = wi * cW - wr * sW;
      wr = nr; wi = ni;
    }
    sS[b16 * 16 + m] = make_float2(sr, si);
  }
  __syncthreads();
  // stage 2: combine with W256^{kb}
  if (tid < 129) {
    int m2 = tid & 15;
    float sK, cK;
    sincosf(TWO_PI_256 * (float)tid, &sK, &cK);  // e^{-i 2pi k/256} = (cK, -sK)
    float fr = 0.f, fi = 0.f, wr = 1.f, wi = 0.f;
#pragma unroll
    for (int bb = 0; bb < 16; ++bb) {
      float2 s = sS[bb * 16 + m2];
      fr = fmaf(s.x, wr, fr); fr = fmaf(-s.y, wi, fr);
      fi = fmaf(s.x, wi, fi); fi = fmaf(s.y, wr, fi);
      float nr = wr * cK + wi * sK;
      float ni = wi * cK - wr * sK;
      wr = nr; wi = ni;
    }
    float2* o = (float2*)Fc;
    o[(size_t)blk * 129 + tid] = make_float2(fr, fi);
  }
}

// ---------------- column DFT (radix-16, 3 channels/block) + stats ----------------
__global__ __launch_bounds__(256) void col_fft_stats(
    const float* __restrict__ Fc, float* __restrict__ mlog, float* __restrict__ ph,
    float* __restrict__ rsum, float* __restrict__ rcnt, float* __restrict__ as1,
    float* __restrict__ as2, float* __restrict__ acnt) {
  const int k = blockIdx.x, b = blockIdx.y;
  const int tid = threadIdx.x;
  const int cp = tid >> 7;          // 2 histogram copies
  __shared__ float2 col[3][256];
  __shared__ float2 sS[3][256];
  __shared__ float l_rs[3][2][32];
  __shared__ float l_rc[32];
  __shared__ float l_s1[3][2][8], l_s2[3][2][8];
  __shared__ float l_ac[8];
  for (int i = tid; i < 192; i += 256) {
    int c = i / 64, r = i % 64;
    l_rs[c][r >> 5][r & 31] = 0.f;
  }
  if (tid < 32) l_rc[tid] = 0.f;
  if (tid < 48) { int c = tid / 16, r = tid % 16; l_s1[c][r >> 3][r & 7] = 0.f; l_s2[c][r >> 3][r & 7] = 0.f; }
  if (tid < 8) l_ac[tid] = 0.f;
  const float2* fc = (const float2*)Fc;
#pragma unroll
  for (int c = 0; c < 3; ++c)
    col[c][tid] = fc[((size_t)((b * 3 + c) * 256) + tid) * 129 + k];
  __syncthreads();
  // stage 1 (complex input)
  {
    int b16 = tid >> 4, m = tid & 15;
    float sW, cW;
    sincosf(TWO_PI_16 * (float)m, &sW, &cW);
#pragma unroll
    for (int c = 0; c < 3; ++c) {
      float sr = 0.f, si = 0.f, wr = 1.f, wi = 0.f;
#pragma unroll
      for (int a = 0; a < 16; ++a) {
        float2 v = col[c][a * 16 + b16];
        sr = fmaf(v.x, wr, sr); sr = fmaf(-v.y, wi, sr);
        si = fmaf(v.x, wi, si); si = fmaf(v.y, wr, si);
        float nr = wr * cW + wi * sW;
        float ni = wi * cW - wr * sW;
        wr = nr; wi = ni;
      }
      sS[c][b16 * 16 + m] = make_float2(sr, si);
    }
  }
  __syncthreads();
  const int j = tid;
  float sK, cK;
  sincosf(TWO_PI_256 * (float)j, &sK, &cK);
  float gr[3], gi[3];
#pragma unroll
  for (int c = 0; c < 3; ++c) {
    float fr = 0.f, fi = 0.f, wr = 1.f, wi = 0.f;
#pragma unroll
    for (int bb = 0; bb < 16; ++bb) {
      float2 s = sS[c][bb * 16 + (j & 15)];
      fr = fmaf(s.x, wr, fr); fr = fmaf(-s.y, wi, fr);
      fi = fmaf(s.x, wi, fi); fi = fmaf(s.y, wr, fi);
      float nr = wr * cK + wi * sK;
      float ni = wi * cK - wr * sK;
      wr = nr; wi = ni;
    }
    gr[c] = fr; gi[c] = fi;
  }
  // bins once per (j,k) (bit-exact fp32 replication of reference index math)
  float fy = (float)(j < 128 ? j : j - 256) * (1.0f / 256.0f);
  float fx = (float)k * (1.0f / 256.0f);
  float rad = sqrtf(fx * fx + fy * fy);
  float denom = sqrtf(0.5f) + 1e-8f;
  int rb = (int)((rad / denom) * 31.0f);
  rb = rb < 0 ? 0 : (rb > 31 ? 31 : rb);
  float ang = atan2f(fy, fx + 1e-8f);
  int ab = (int)((ang + PI_F) / (2.0f * PI_F) * 8.0f);
  ab = ab < 0 ? 0 : (ab > 7 ? 7 : ab);
#pragma unroll
  for (int c = 0; c < 3; ++c) {
    float mag = sqrtf(gr[c] * gr[c] + gi[c] * gi[c]);
    mag = fminf(fmaxf(mag, 1e-8f), 1e6f);
    float ml = fminf(fmaxf(log1pf(mag), -20.f), 20.f);
    float p = fminf(fmaxf(atan2f(gi[c], gr[c]) / PI_F, -1.f), 1.f);
    size_t oidx = ((size_t)((b * 3 + c) * 256) + j) * 129 + k;   // j-major
    mlog[oidx] = ml;
    ph[oidx] = p;
    atomicAdd(&l_rs[c][cp][rb], mag);
    atomicAdd(&l_s1[c][cp][ab], mag);
    atomicAdd(&l_s2[c][cp][ab], mag * mag);
  }
  if (b == 0) {
    atomicAdd(&l_rc[rb], 1.0f);
    atomicAdd(&l_ac[ab], 1.0f);
  }
  __syncthreads();
  if (tid < 96) {
    int c = tid / 32, i2 = tid % 32;
    atomicAdd(&rsum[(b * 3 + c) * 32 + i2], l_rs[c][0][i2] + l_rs[c][1][i2]);
  } else if (tid < 120) {
    int t2 = tid - 96;
    int c = t2 / 8, a2 = t2 % 8;
    atomicAdd(&as1[(b * 3 + c) * 8 + a2], l_s1[c][0][a2] + l_s1[c][1][a2]);
    atomicAdd(&as2[(b * 3 + c) * 8 + a2], l_s2[c][0][a2] + l_s2[c][1][a2]);
  }
  if (b == 0) {
    if (tid < 32) atomicAdd(&rcnt[tid], l_rc[tid]);
    else if (tid < 40) atomicAdd(&acnt[tid - 32], l_ac[tid - 32]);
  }
}

// ---------------- fused upsample -> conv1(MFMA) -> conv2(MFMA) -> pool ----------------
// Round-5 structure VERBATIM (measured 155 us, FETCH 16.6 MB, no spill): full f1
// in LDS (no K-split), 16x16 tile, 4 waves, wave = (oc-group ntg, row-half).
// conv2 B: C2=64 rolling distance-1 register prefetch; C2=32 all 9 preloaded.
// Separate __global__ instantiations per branch (rounds 7-9: other combos spilled
// to scratch -> 1.1 GB HBM; do NOT merge or add prefetch to a K-split hf loop).
template <int C2>
__global__ __launch_bounds__(256, 2) void conv_mfma(
    const float* __restrict__ src,           // [B,3,256,129] spectral plane (j-major)
    const unsigned short* __restrict__ w1b,  // [C2][32] bf16 conv1 weights
    const unsigned short* __restrict__ wB,   // [9][C2][C2] bf16 conv2 [pos][oc][ci]
    const float* __restrict__ s1, const float* __restrict__ t1,
    const float* __restrict__ s2, const float* __restrict__ t2,
    float* __restrict__ pool) {
  constexpr int ST = C2 + 8;                 // f1 row stride (16B-aligned rows)
  constexpr int NT = C2 / 16;                // total oc tiles
  constexpr int WNT = (C2 == 64) ? 2 : 1;    // oc tiles per wave
  constexpr int KS = C2 / 32;                // conv2 K steps per kx
  constexpr int NG = 3 * KS;                 // (kx,ks) granules

  __shared__ float s_in[3][20][20];
  __shared__ float s_sc1[C2], s_sh1[C2];
  __shared__ __align__(16) unsigned short s_f1[324 * ST];

  const int tid = threadIdx.x;
  const int b = blockIdx.z;
  const int tx0 = blockIdx.x * 16, ty0 = blockIdx.y * 16;
  const int lane = tid & 63, wv = tid >> 6;
  const int ln = lane & 15, q = lane >> 4;
  const int ntg = wv & 1, half = wv >> 1;
  const int ocb0 = ntg * WNT * 16;

  // stage input tile (halo 2) with fused bilinear W-upsample (129 -> 256)
  for (int idx = tid; idx < 1200; idx += 256) {
    int c = idx / 400, r = idx % 400, iy = r / 20, ix = r % 20;
    int gy = ty0 - 2 + iy, gx = tx0 - 2 + ix;
    float v = 0.f;
    if ((unsigned)gy < 256u && (unsigned)gx < 256u) {
      float srcx = ((float)gx + 0.5f) * (129.0f / 256.0f) - 0.5f;
      float fl = floorf(srcx);
      float w = srcx - fl;
      int x0 = (int)fl, x1 = x0 + 1;
      x0 = x0 < 0 ? 0 : x0;
      x1 = x1 > 128 ? 128 : x1;
      const float* rowp = src + ((size_t)(b * 3 + c) * 256 + gy) * 129;
      v = rowp[x0] * (1.f - w) + rowp[x1] * w;
    }
    s_in[c][iy][ix] = v;
  }
  if (tid < C2) { s_sc1[tid] = s1[tid]; s_sh1[tid] = t1[tid]; }

  // conv1 A-side weights (all oc tiles; A[m=oc][k=tap])
  bf16x8 b1[NT];
#pragma unroll
  for (int nt = 0; nt < NT; ++nt)
    b1[nt] = *(const bf16x8*)&w1b[(nt * 16 + ln) * 32 + q * 8];

  // conv2 B prefetch (issued before conv1 so the pipe is warm at conv2 start)
  bf16x8 Bb[2][3 * WNT];     // rolling (C2==64)
  bf16x8 Bw[(C2 == 32) ? 9 : 1];
  if constexpr (C2 == 64) {
#pragma unroll
    for (int ky = 0; ky < 3; ++ky)
#pragma unroll
      for (int w = 0; w < 2; ++w)
        Bb[0][ky * 2 + w] =
            *(const bf16x8*)&wB[((size_t)(ky * 3) * 64 + ocb0 + w * 16 + ln) * 64 + q * 8];
  } else {
#pragma unroll
    for (int kx = 0; kx < 3; ++kx)
#pragma unroll
      for (int ky = 0; ky < 3; ++ky)
        Bw[kx * 3 + ky] =
            *(const bf16x8*)&wB[((size_t)(ky * 3 + kx) * 32 + ocb0 + ln) * 32 + q * 8];
  }

  __syncthreads();

  // BN params for conv1 writeback (oc = nt*16 + q*4 + r)
  float c1sc[NT][4], c1sh[NT][4];
#pragma unroll
  for (int nt = 0; nt < NT; ++nt)
#pragma unroll
    for (int r = 0; r < 4; ++r) {
      c1sc[nt][r] = s_sc1[nt * 16 + q * 4 + r];
      c1sh[nt][r] = s_sh1[nt * 16 + q * 4 + r];
    }

  // ---- phase 1: conv1 via MFMA (D[oc][pixel]); 18x18 halo = 324 px in 21 m-tiles ----
  const float* sp = &s_in[0][0][0];
  int koff[8];
#pragma unroll
  for (int j = 0; j < 8; ++j) {
    int k = q * 8 + j;  // k = c*9 + dy*3 + dx
    if (k < 27) {
      int c = k / 9, rr = k - c * 9, dy = rr / 3, dx = rr - dy * 3;
      koff[j] = (c * 20 + dy) * 20 + dx;
    } else koff[j] = -1;
  }
  for (int mt = wv; mt < 21; mt += 4) {
    int p = mt * 16 + ln;
    int pc = p < 324 ? p : 0;           // dummy pixel for pad lanes (cols discarded)
    int py = pc / 18, px = pc - py * 18;
    int pix = py * 20 + px;
    union { bf16x8 v; unsigned u[4]; } af;
#pragma unroll
    for (int jj = 0; jj < 4; ++jj) {
      float v0 = (koff[2 * jj] >= 0) ? sp[koff[2 * jj] + pix] : 0.f;
      float v1 = (koff[2 * jj + 1] >= 0) ? sp[koff[2 * jj + 1] + pix] : 0.f;
      af.u[jj] = (unsigned)f2bf(v0) | ((unsigned)f2bf(v1) << 16);
    }
    bool inim = false;
    if (p < 324) {
      int gy = ty0 - 1 + py, gx = tx0 - 1 + px;
      inim = ((unsigned)gy < 256u) && ((unsigned)gx < 256u);
    }
#pragma unroll
    for (int nt = 0; nt < NT; ++nt) {
      f32x4 c1 = __builtin_amdgcn_mfma_f32_16x16x32_bf16(
          b1[nt], af.v, (f32x4){0.f, 0.f, 0.f, 0.f}, 0, 0, 0);
      if (p < 324) {
        float v0 = inim ? fmaxf(fmaf(c1[0], c1sc[nt][0], c1sh[nt][0]), 0.f) : 0.f;
        float v1 = inim ? fmaxf(fmaf(c1[1], c1sc[nt][1], c1sh[nt][1]), 0.f) : 0.f;
        float v2 = inim ? fmaxf(fmaf(c1[2], c1sc[nt][2], c1sh[nt][2]), 0.f) : 0.f;
        float v3 = inim ? fmaxf(fmaf(c1[3], c1sc[nt][3], c1sh[nt][3]), 0.f) : 0.f;
        uint2 pk;
        pk.x = (unsigned)f2bf(v0) | ((unsigned)f2bf(v1) << 16);
        pk.y = (unsigned)f2bf(v2) | ((unsigned)f2bf(v3) << 16);
        *(uint2*)&s_f1[p * ST + nt * 16 + q * 4] = pk;  // 8B aligned
      }
    }
  }
  __syncthreads();

  // ---- phase 2: conv2 implicit GEMM; wave = WNT oc-tiles x 8 pixel-rows ----
  f32x4 acc[WNT][8];
#pragma unroll
  for (int w = 0; w < WNT; ++w)
#pragma unroll
    for (int i = 0; i < 8; ++i)
      acc[w][i] = (f32x4){0.f, 0.f, 0.f, 0.f};

  const int rbase = half * 8;
#pragma unroll
  for (int g = 0; g < NG; ++g) {
    const int kx = g / KS, ks = g % KS;
    if constexpr (C2 == 64) {
      if (g + 1 < NG) {
        const int nkx = (g + 1) / KS, nks = (g + 1) % KS;
#pragma unroll
        for (int ky = 0; ky < 3; ++ky)
#pragma unroll
          for (int w = 0; w < 2; ++w)
            Bb[(g + 1) & 1][ky * 2 + w] =
                *(const bf16x8*)&wB[((size_t)(ky * 3 + nkx) * 64 + ocb0 + w * 16 + ln) * 64 +
                                    nks * 32 + q * 8];
      }
    }
    bf16x8 a[10];
#pragma unroll
    for (int rr = 0; rr < 10; ++rr)
      a[rr] = *(const bf16x8*)&s_f1[((rbase + rr) * 18 + ln + kx) * ST + ks * 32 + q * 8];
#pragma unroll
    for (int ky = 0; ky < 3; ++ky)
#pragma unroll
      for (int w = 0; w < WNT; ++w) {
        bf16x8 bf;
        if constexpr (C2 == 64) bf = Bb[g & 1][ky * 2 + w];
        else bf = Bw[kx * 3 + ky];
#pragma unroll
        for (int i = 0; i < 8; ++i)
          acc[w][i] = __builtin_amdgcn_mfma_f32_16x16x32_bf16(a[i + ky], bf, acc[w][i], 0, 0, 0);
      }
  }

  // epilogue: BN+ReLU + pool partial. D: col(ln)=oc, rows=pixel cols (q*4+r).
#pragma unroll
  for (int w = 0; w < WNT; ++w) {
    const int oc = ocb0 + w * 16 + ln;
    const float sc = s2[oc], sh = t2[oc];
    float v = 0.f;
#pragma unroll
    for (int i = 0; i < 8; ++i)
#pragma unroll
      for (int r = 0; r < 4; ++r)
        v += fmaxf(fmaf(acc[w][i][r], sc, sh), 0.f);
    v += __shfl_xor(v, 16);
    v += __shfl_xor(v, 32);
    if (q == 0) atomicAdd(&pool[b * C2 + oc], v);
  }
}

// ---------------- final: radial conv branch + comb + linear/LN/relu/linear ----------------
__global__ __launch_bounds__(256) void final_mlp(
    const float* __restrict__ rsum, const float* __restrict__ rcnt,
    const float* __restrict__ rw1, const float* __restrict__ rw2,
    const float* __restrict__ sr1, const float* __restrict__ tr1,
    const float* __restrict__ sr2, const float* __restrict__ tr2,
    const float* __restrict__ mpool, const float* __restrict__ ppool,
    const float* __restrict__ as1, const float* __restrict__ as2,
    const float* __restrict__ acnt,
    const float* __restrict__ lw1, const float* __restrict__ lb1,
    const float* __restrict__ lng, const float* __restrict__ lnb,
    const float* __restrict__ lw2, const float* __restrict__ lb2,
    float* __restrict__ out) {
  int b = blockIdx.x, t = threadIdx.x;
  __shared__ float rad[3][32];
  __shared__ float rf1[32][32];
  __shared__ float rf2[32][32];
  __shared__ float rfv[32];
  __shared__ float comb[176];
  __shared__ float red[256];
  __shared__ float hrelu[256];
  __shared__ float s_mu, s_var;

  if (t < 96) {
    int c = t / 32, i = t % 32;
    float cnt = fmaxf(rcnt[i], 1.0f);
    float v = rsum[(b * 3 + c) * 32 + i] / cnt;
    rad[c][i] = fminf(fmaxf(v, 0.f), 1e6f);
  }
  __syncthreads();
  for (int idx = t; idx < 1024; idx += 256) {
    int oc = idx >> 5, i = idx & 31;
    float a = 0.f;
    for (int c = 0; c < 3; ++c)
#pragma unroll
      for (int d = 0; d < 3; ++d) {
        int ii = i + d - 1;
        if (ii >= 0 && ii < 32) a = fmaf(rad[c][ii], rw1[(oc * 3 + c) * 3 + d], a);
      }
    rf1[oc][i] = fmaxf(fmaf(a, sr1[oc], tr1[oc]), 0.f);
  }
  __syncthreads();
  for (int idx = t; idx < 1024; idx += 256) {
    int oc = idx >> 5, i = idx & 31;
    float a = 0.f;
    for (int c = 0; c < 32; ++c)
#pragma unroll
      for (int d = 0; d < 3; ++d) {
        int ii = i + d - 1;
        if (ii >= 0 && ii < 32) a = fmaf(rf1[c][ii], rw2[(oc * 32 + c) * 3 + d], a);
      }
    rf2[oc][i] = fmaxf(fmaf(a, sr2[oc], tr2[oc]), 0.f);
  }
  __syncthreads();
  if (t < 32) {
    float s = 0.f;
    for (int i = 0; i < 32; ++i) s += rf2[t][i];
    rfv[t] = s * (1.0f / 32.0f);
  }
  __syncthreads();

  if (t < 64) comb[t] = fix_nan(mpool[b * 64 + t] * (1.0f / 65536.0f), 1e4f, -1e4f);
  else if (t < 96) comb[t] = fix_nan(ppool[b * 32 + t - 64] * (1.0f / 65536.0f), 1e4f, -1e4f);
  else if (t < 128) comb[t] = fix_nan(rfv[t - 96], 1e4f, -1e4f);
  else if (t < 176) {
    int j = t - 128;
    int a = j / 6, r = j % 6, m = r / 3, c = r % 3;
    float cnt = acnt[a];
    float v = 0.f;  // empty sector -> NaN -> nan_to_num -> 0
    if (cnt > 0.f) {
      float s1v = as1[(b * 3 + c) * 8 + a], s2v = as2[(b * 3 + c) * 8 + a];
      float mean = s1v / cnt;
      if (m == 0)
        v = mean;
      else {
        float var = (s2v - cnt * mean * mean) / fmaxf(cnt - 1.f, 1.f);
        v = sqrtf(fmaxf(var, 0.f));
      }
    }
    comb[t] = fix_nan(v, 1e4f, -1e4f);
  }
  __syncthreads();
  float h = lb1[t];
  const float* wr = lw1 + t * 176;
#pragma unroll 8
  for (int j = 0; j < 176; ++j) h = fmaf(comb[j], wr[j], h);
  red[t] = h;
  __syncthreads();
  for (int s = 128; s > 0; s >>= 1) {
    if (t < s) red[t] += red[t + s];
    __syncthreads();
  }
  if (t == 0) s_mu = red[0] * (1.0f / 256.0f);
  __syncthreads();
  float mu = s_mu;
  float d = h - mu;
  red[t] = d * d;
  __syncthreads();
  for (int s = 128; s > 0; s >>= 1) {
    if (t < s) red[t] += red[t + s];
    __syncthreads();
  }
  if (t == 0) s_var = red[0] * (1.0f / 256.0f);
  __syncthreads();
  float hn = d / sqrtf(s_var + 1e-5f) * lng[t] + lnb[t];
  hrelu[t] = fmaxf(hn, 0.f);
  __syncthreads();
  if (t < 128) {
    float o = lb2[t];
    const float* w2r = lw2 + t * 256;
#pragma unroll 8
    for (int j = 0; j < 256; ++j) o = fmaf(hrelu[j], w2r[j], o);
    o = fminf(fmaxf(o, -100.f), 100.f);
    out[b * 128 + t] = fix_nan(o, 100.f, -100.f);
  }
}

// ---------------- host launcher ----------------
extern "C" void kernel_launch(void* const* d_in, const int* in_sizes, int n_in,
                              void* d_out, int out_size, void* d_ws, size_t ws_size,
                              hipStream_t stream) {
  const float* x    = (const float*)d_in[0];
  const float* mw1  = (const float*)d_in[1];
  const float* mb1  = (const float*)d_in[2];
  const float* mbn1 = (const float*)d_in[3];
  const float* mw2  = (const float*)d_in[4];
  const float* mb2  = (const float*)d_in[5];
  const float* mbn2 = (const float*)d_in[6];
  const float* pw1  = (const float*)d_in[7];
  const float* pb1  = (const float*)d_in[8];
  const float* pbn1 = (const float*)d_in[9];
  const float* pw2  = (const float*)d_in[10];
  const float* pb2  = (const float*)d_in[11];
  const float* pbn2 = (const float*)d_in[12];
  const float* rw1  = (const float*)d_in[13];
  const float* rb1  = (const float*)d_in[14];
  const float* rbn1 = (const float*)d_in[15];
  const float* rw2  = (const float*)d_in[16];
  const float* rb2  = (const float*)d_in[17];
  const float* rbn2 = (const float*)d_in[18];
  const float* lw1  = (const float*)d_in[19];
  const float* lb1  = (const float*)d_in[20];
  const float* lng  = (const float*)d_in[21];
  const float* lnb  = (const float*)d_in[22];
  const float* lw2  = (const float*)d_in[23];
  const float* lb2  = (const float*)d_in[24];

  float* ws = (float*)d_ws;
  float* out = (float*)d_out;

  float* fc    = ws + OFF_FC;
  float* mlog  = ws + OFF_MLOG;
  float* phb   = ws + OFF_PH;
  float* rsum  = ws + OFF_RSUM;
  float* rcnt  = ws + OFF_RCNT;
  float* as1   = ws + OFF_AS1;
  float* as2   = ws + OFF_AS2;
  float* acnt  = ws + OFF_ACNT;
  float* mpool = ws + OFF_MPOOL;
  float* ppool = ws + OFF_PPOOL;
  float* par   = ws + OFF_PAR;
  unsigned short* wbm  = (unsigned short*)(ws + OFF_WBM);
  unsigned short* wbp  = (unsigned short*)(ws + OFF_WBP);
  unsigned short* w1bm = (unsigned short*)(ws + OFF_W1BM);
  unsigned short* w1bp = (unsigned short*)(ws + OFF_W1BP);

  row_fft_prep<<<12481, 256, 0, stream>>>(x, fc, rsum,
                                          mw1, pw1, mw2, pw2, mb1, mbn1, mb2, mbn2,
                                          pb1, pbn1, pb2, pbn2, rb1, rbn1, rb2, rbn2,
                                          par, wbm, wbp, w1bm, w1bp);
  col_fft_stats<<<dim3(129, 16), 256, 0, stream>>>(fc, mlog, phb, rsum, rcnt,
                                                   as1, as2, acnt);
  conv_mfma<64><<<dim3(16, 16, 16), 256, 0, stream>>>(
      mlog, w1bm, wbm, par + 0, par + 64, par + 128, par + 192, mpool);
  conv_mfma<32><<<dim3(16, 16, 16), 256, 0, stream>>>(
      phb, w1bp, wbp, par + 256, par + 288, par + 320, par + 352, ppool);
  final_mlp<<<16, 256, 0, stream>>>(rsum, rcnt, rw1, rw2, par + 384, par + 416,
                                    par + 448, par + 480, mpool, ppool, as1, as2,
                                    acnt, lw1, lb1, lng, lnb, lw2, lb2, out);
}

// Round 11
// 435.837 us; speedup vs baseline: 1.3418x; 1.0168x over previous
//
#include <hip/hip_runtime.h>
#include <math.h>

#define PI_F 3.14159274101257324f   // float(np.pi)
#define TWO_PI_256 0.02454369260617026f   // 2*pi/256
#define TWO_PI_16  0.39269908169872414f   // 2*pi/16

typedef __attribute__((ext_vector_type(8))) short bf16x8;   // 4 VGPRs
typedef __attribute__((ext_vector_type(4))) float f32x4;

// ---------------- workspace layout (float offsets) ----------------
static const size_t OFF_FC    = 0;                    // row-FFT complex out [B*C*256][129]*2
static const size_t OFF_MLOG  = 3170304;              // [B,C,256,129]  (j-major: staging-coalesced)
static const size_t OFF_PH    = 4755456;              // [B,C,256,129]
static const size_t OFF_RSUM  = 9486336;              // [B,C,32]
static const size_t OFF_RCNT  = OFF_RSUM + 1536;      // [32]
static const size_t OFF_AS1   = OFF_RCNT + 32;        // [B,C,8]
static const size_t OFF_AS2   = OFF_AS1 + 384;        // [B,C,8]
static const size_t OFF_ACNT  = OFF_AS2 + 384;        // [8]
static const size_t OFF_MPOOL = OFF_ACNT + 8;         // [B,64]
static const size_t OFF_PPOOL = OFF_MPOOL + 1024;     // [B,32]
static const size_t OFF_RF    = OFF_PPOOL + 512;      // (unused)
static const size_t OFF_PAR   = OFF_RF + 512;         // 512 folded BN params
static const size_t OFF_WBM   = OFF_PAR + 512;        // mag conv2 w [9][64][64] bf16
static const size_t OFF_WBP   = OFF_WBM + 18432;      // ph conv2 w [9][32][32] bf16
static const size_t OFF_W1BM  = OFF_WBP + 4608;       // mag conv1 w [64][32] bf16
static const size_t OFF_W1BP  = OFF_W1BM + 1024;      // ph conv1 w [32][32] bf16
// param sub-offsets: sm1 0, tm1 64, sm2 128, tm2 192, sp1 256, tp1 288, sp2 320, tp2 352,
//                    sr1 384, tr1 416, sr2 448, tr2 480

__device__ __forceinline__ float fix_nan(float v, float pinf, float ninf) {
  if (isnan(v)) return 0.f;
  if (isinf(v)) return v > 0.f ? pinf : ninf;
  return v;
}

__device__ __forceinline__ unsigned short f2bf(float f) {
  unsigned u = __float_as_uint(f);
  unsigned r = (u + 0x7FFFu + ((u >> 16) & 1u)) >> 16;   // RNE (finite values only)
  return (unsigned short)r;
}

__device__ __forceinline__ void fold_bn(const float* bn, int C, int c, float cb,
                                        float* s, float* t) {
  float g = bn[c], b = bn[C + c], m = bn[2 * C + c], v = bn[3 * C + c];
  float sc = g / sqrtf(v + 1e-5f);
  *s = sc;
  *t = b + (cb - m) * sc;
}

// ---------------- row rFFT (radix-16, 2 rows/block) + fused prep + zeroing ----------------
// blocks 0..6143: rows 2*blk, 2*blk+1 (stage-2's tid<129 half now does both rows,
// sharing sincos + rotation). blocks >= 6144: weight/BN prep. block 0 zeroes accums.
__global__ __launch_bounds__(256) void row_fft_prep(
    const float* __restrict__ x, float* __restrict__ Fc, float* __restrict__ zbuf,
    const float* __restrict__ mw1, const float* __restrict__ pw1,
    const float* __restrict__ mw2, const float* __restrict__ pw2,
    const float* __restrict__ mb1, const float* __restrict__ mbn1,
    const float* __restrict__ mb2, const float* __restrict__ mbn2,
    const float* __restrict__ pb1, const float* __restrict__ pbn1,
    const float* __restrict__ pb2, const float* __restrict__ pbn2,
    const float* __restrict__ rb1, const float* __restrict__ rbn1,
    const float* __restrict__ rb2, const float* __restrict__ rbn2,
    float* __restrict__ par, unsigned short* __restrict__ wbm,
    unsigned short* __restrict__ wbp, unsigned short* __restrict__ w1bm,
    unsigned short* __restrict__ w1bp) {
  const int blk = blockIdx.x;
  const int tid = threadIdx.x;
  if (blk >= 6144) {
    int idx = (blk - 6144) * 256 + tid;
    if (idx < 36864) {
      int pos = idx / 4096, rem = idx % 4096;
      int oc = rem >> 6, ci = rem & 63;
      wbm[idx] = f2bf(mw2[(oc * 64 + ci) * 9 + pos]);
    } else if (idx < 46080) {
      int i = idx - 36864;
      int pos = i / 1024, rem = i % 1024;
      int oc = rem >> 5, ci = rem & 31;
      wbp[i] = f2bf(pw2[(oc * 32 + ci) * 9 + pos]);
    } else if (idx < 46336) {
      int i = idx - 46080;  // 0..255
      float s, t;
      if (i < 64)       { fold_bn(mbn1, 64, i, mb1[i], &s, &t);          par[i] = s;       par[64 + i] = t; }
      else if (i < 128) { int c = i - 64;  fold_bn(mbn2, 64, c, mb2[c], &s, &t); par[128 + c] = s; par[192 + c] = t; }
      else if (i < 160) { int c = i - 128; fold_bn(pbn1, 32, c, pb1[c], &s, &t); par[256 + c] = s; par[288 + c] = t; }
      else if (i < 192) { int c = i - 160; fold_bn(pbn2, 32, c, pb2[c], &s, &t); par[320 + c] = s; par[352 + c] = t; }
      else if (i < 224) { int c = i - 192; fold_bn(rbn1, 32, c, rb1[c], &s, &t); par[384 + c] = s; par[416 + c] = t; }
      else              { int c = i - 224; fold_bn(rbn2, 32, c, rb2[c], &s, &t); par[448 + c] = s; par[480 + c] = t; }
    } else if (idx < 48384) {
      int i = idx - 46336;                 // conv1 mag w [oc][k], k=c*9+dy*3+dx, pad->0
      int oc = i >> 5, k = i & 31;
      w1bm[i] = (k < 27) ? f2bf(mw1[oc * 27 + k]) : (unsigned short)0;
    } else if (idx < 49408) {
      int i = idx - 48384;
      int oc = i >> 5, k = i & 31;
      w1bp[i] = (k < 27) ? f2bf(pw1[oc * 27 + k]) : (unsigned short)0;
    }
    return;
  }
  if (blk == 0) {
    for (int i = tid; i < 3880; i += 256) zbuf[i] = 0.f;   // rsum..ppool accumulators
  }
  __shared__ float xr[2][256];
  __shared__ float2 sS[2][256];
  for (int i = tid; i < 512; i += 256) {
    int rw = i >> 8, w = i & 255;
    float v = x[((size_t)blk * 2 + rw) * 256 + w];
    xr[rw][w] = fminf(fmaxf(v, -10.f), 10.f);
  }
  __syncthreads();
  // stage 1: both rows with shared twiddle rotation (per-row op order unchanged)
  {
    int b16 = tid >> 4, m = tid & 15;
    float sW, cW;
    sincosf(TWO_PI_16 * (float)m, &sW, &cW);   // W = e^{-i 2pi m/16}
    float sr0 = 0.f, si0 = 0.f, sr1 = 0.f, si1 = 0.f, wr = 1.f, wi = 0.f;
#pragma unroll
    for (int a = 0; a < 16; ++a) {
      float x0 = xr[0][a * 16 + b16];
      float x1 = xr[1][a * 16 + b16];
      sr0 = fmaf(x0, wr, sr0);
      si0 = fmaf(x0, wi, si0);
      sr1 = fmaf(x1, wr, sr1);
      si1 = fmaf(x1, wi, si1);
      float nr = wr * cW + wi * sW;
      float ni = wi * cW - wr * sW;
      wr = nr; wi = ni;
    }
    sS[0][b16 * 16 + m] = make_float2(sr0, si0);
    sS[1][b16 * 16 + m] = make_float2(sr1, si1);
  }
  __syncthreads();
  // stage 2: combine with W256^{kb}, both rows per thread
  if (tid < 129) {
    int m2 = tid & 15;
    float sK, cK;
    sincosf(TWO_PI_256 * (float)tid, &sK, &cK);
    float fr0 = 0.f, fi0 = 0.f, fr1 = 0.f, fi1 = 0.f, wr = 1.f, wi = 0.f;
#pragma unroll
    for (int bb = 0; bb < 16; ++bb) {
      float2 s0 = sS[0][bb * 16 + m2];
      float2 s1 = sS[1][bb * 16 + m2];
      fr0 = fmaf(s0.x, wr, fr0); fr0 = fmaf(-s0.y, wi, fr0);
      fi0 = fmaf(s0.x, wi, fi0); fi0 = fmaf(s0.y, wr, fi0);
      fr1 = fmaf(s1.x, wr, fr1); fr1 = fmaf(-s1.y, wi, fr1);
      fi1 = fmaf(s1.x, wi, fi1); fi1 = fmaf(s1.y, wr, fi1);
      float nr = wr * cK + wi * sK;
      float ni = wi * cK - wr * sK;
      wr = nr; wi = ni;
    }
    float2* o = (float2*)Fc;
    o[((size_t)blk * 2 + 0) * 129 + tid] = make_float2(fr0, fi0);
    o[((size_t)blk * 2 + 1) * 129 + tid] = make_float2(fr1, fi1);
  }
}

// ---------------- column DFT (radix-16, 4 k-columns/block, coalesced) + stats ----------------
// Round-10 postmortem: old layout read Fc at 1032 B/lane stride -> 64 lines per
// wave-load. New: block = (kg of 4 k, b, c); loads put 4 consecutive lanes on 32 B
// contiguous (4x fewer line transactions). Per-column DFT op order is IDENTICAL
// to the verified radix-16 (bit-exact results); twiddle rotation shared across kk.
__global__ __launch_bounds__(256) void col_fft_stats(
    const float* __restrict__ Fc, float* __restrict__ mlog, float* __restrict__ ph,
    float* __restrict__ rsum, float* __restrict__ rcnt, float* __restrict__ as1,
    float* __restrict__ as2, float* __restrict__ acnt) {
  const int kg = blockIdx.x;          // 0..32 (k = kg*4+kk; kg==32 -> only k=128)
  const int b  = blockIdx.y;          // 0..15
  const int c  = blockIdx.z;          // 0..2
  const int bc = b * 3 + c;
  const int tid = threadIdx.x;
  const int cp = tid >> 7;            // 2 histogram copies
  const int k0 = kg * 4;
  __shared__ float2 colt[4][256];     // [kk][y]  (stage-1 reads bank-clean)
  __shared__ float2 sSt[4][256];      // [kk][b16*16+m]
  __shared__ float l_rs[2][32];
  __shared__ float l_rc[32];
  __shared__ float l_s1[2][8], l_s2[2][8];
  __shared__ float l_ac[8];
  if (tid < 64) l_rs[tid >> 5][tid & 31] = 0.f;
  if (tid < 32) l_rc[tid] = 0.f;
  if (tid < 16) { l_s1[tid >> 3][tid & 7] = 0.f; l_s2[tid >> 3][tid & 7] = 0.f; }
  if (tid < 8) l_ac[tid] = 0.f;
  const float2* fc = (const float2*)Fc;
  for (int idx = tid; idx < 1024; idx += 256) {
    int y = idx >> 2, kk = idx & 3;
    int k = k0 + kk;
    k = k > 128 ? 128 : k;            // clamp (kg==32 dups; output-guarded)
    colt[kk][y] = fc[((size_t)(bc * 256) + y) * 129 + k];
  }
  __syncthreads();
  // stage 1 (complex input), 4 columns with shared rotation
  {
    int b16 = tid >> 4, m = tid & 15;
    float sW, cW;
    sincosf(TWO_PI_16 * (float)m, &sW, &cW);
    float sr[4] = {0.f, 0.f, 0.f, 0.f}, si[4] = {0.f, 0.f, 0.f, 0.f};
    float wr = 1.f, wi = 0.f;
#pragma unroll
    for (int a = 0; a < 16; ++a) {
#pragma unroll
      for (int kk = 0; kk < 4; ++kk) {
        float2 v = colt[kk][a * 16 + b16];
        sr[kk] = fmaf(v.x, wr, sr[kk]); sr[kk] = fmaf(-v.y, wi, sr[kk]);
        si[kk] = fmaf(v.x, wi, si[kk]); si[kk] = fmaf(v.y, wr, si[kk]);
      }
      float nr = wr * cW + wi * sW;
      float ni = wi * cW - wr * sW;
      wr = nr; wi = ni;
    }
#pragma unroll
    for (int kk = 0; kk < 4; ++kk)
      sSt[kk][b16 * 16 + m] = make_float2(sr[kk], si[kk]);
  }
  __syncthreads();
  const int j = tid;
  float sK, cK;
  sincosf(TWO_PI_256 * (float)j, &sK, &cK);
  float gr[4] = {0.f, 0.f, 0.f, 0.f}, gi[4] = {0.f, 0.f, 0.f, 0.f};
  {
    const int m2 = j & 15;
    float wr = 1.f, wi = 0.f;
#pragma unroll
    for (int bb = 0; bb < 16; ++bb) {
#pragma unroll
      for (int kk = 0; kk < 4; ++kk) {
        float2 s = sSt[kk][bb * 16 + m2];
        gr[kk] = fmaf(s.x, wr, gr[kk]); gr[kk] = fmaf(-s.y, wi, gr[kk]);
        gi[kk] = fmaf(s.x, wi, gi[kk]); gi[kk] = fmaf(s.y, wr, gi[kk]);
      }
      float nr = wr * cK + wi * sK;
      float ni = wi * cK - wr * sK;
      wr = nr; wi = ni;
    }
  }
  // outputs + bins per kk (bit-exact fp32 replication of reference index math)
  float fy = (float)(j < 128 ? j : j - 256) * (1.0f / 256.0f);
  const float denom = sqrtf(0.5f) + 1e-8f;
#pragma unroll
  for (int kk = 0; kk < 4; ++kk) {
    int k = k0 + kk;
    if (k > 128) break;
    float fx = (float)k * (1.0f / 256.0f);
    float rad = sqrtf(fx * fx + fy * fy);
    int rb = (int)((rad / denom) * 31.0f);
    rb = rb < 0 ? 0 : (rb > 31 ? 31 : rb);
    float ang = atan2f(fy, fx + 1e-8f);
    int ab = (int)((ang + PI_F) / (2.0f * PI_F) * 8.0f);
    ab = ab < 0 ? 0 : (ab > 7 ? 7 : ab);
    float mag = sqrtf(gr[kk] * gr[kk] + gi[kk] * gi[kk]);
    mag = fminf(fmaxf(mag, 1e-8f), 1e6f);
    float ml = fminf(fmaxf(log1pf(mag), -20.f), 20.f);
    float p = fminf(fmaxf(atan2f(gi[kk], gr[kk]) / PI_F, -1.f), 1.f);
    size_t oidx = ((size_t)(bc * 256) + j) * 129 + k;   // j-major
    mlog[oidx] = ml;
    ph[oidx] = p;
    atomicAdd(&l_rs[cp][rb], mag);
    atomicAdd(&l_s1[cp][ab], mag);
    atomicAdd(&l_s2[cp][ab], mag * mag);
    if (b == 0 && c == 0) {
      atomicAdd(&l_rc[rb], 1.0f);
      atomicAdd(&l_ac[ab], 1.0f);
    }
  }
  __syncthreads();
  if (tid < 32) {
    atomicAdd(&rsum[bc * 32 + tid], l_rs[0][tid] + l_rs[1][tid]);
  } else if (tid < 40) {
    int a = tid - 32;
    atomicAdd(&as1[bc * 8 + a], l_s1[0][a] + l_s1[1][a]);
    atomicAdd(&as2[bc * 8 + a], l_s2[0][a] + l_s2[1][a]);
  }
  if (b == 0 && c == 0) {
    if (tid < 32) atomicAdd(&rcnt[tid], l_rc[tid]);
    else if (tid < 40) atomicAdd(&acnt[tid - 32], l_ac[tid - 32]);
  }
}

// ---------------- fused upsample -> conv1(MFMA) -> conv2(MFMA) -> pool ----------------
// Round-10 kernel FROZEN (152.9 us, FETCH 16.6 MB, VGPR 72, no spill). Do NOT
// merge branches, K-split with prefetch, or transpose the src layout (rounds 7-9).
template <int C2>
__global__ __launch_bounds__(256, 2) void conv_mfma(
    const float* __restrict__ src,           // [B,3,256,129] spectral plane (j-major)
    const unsigned short* __restrict__ w1b,  // [C2][32] bf16 conv1 weights
    const unsigned short* __restrict__ wB,   // [9][C2][C2] bf16 conv2 [pos][oc][ci]
    const float* __restrict__ s1, const float* __restrict__ t1,
    const float* __restrict__ s2, const float* __restrict__ t2,
    float* __restrict__ pool) {
  constexpr int ST = C2 + 8;                 // f1 row stride (16B-aligned rows)
  constexpr int NT = C2 / 16;                // total oc tiles
  constexpr int WNT = (C2 == 64) ? 2 : 1;    // oc tiles per wave
  constexpr int KS = C2 / 32;                // conv2 K steps per kx
  constexpr int NG = 3 * KS;                 // (kx,ks) granules

  __shared__ float s_in[3][20][20];
  __shared__ float s_sc1[C2], s_sh1[C2];
  __shared__ __align__(16) unsigned short s_f1[324 * ST];

  const int tid = threadIdx.x;
  const int b = blockIdx.z;
  const int tx0 = blockIdx.x * 16, ty0 = blockIdx.y * 16;
  const int lane = tid & 63, wv = tid >> 6;
  const int ln = lane & 15, q = lane >> 4;
  const int ntg = wv & 1, half = wv >> 1;
  const int ocb0 = ntg * WNT * 16;

  // stage input tile (halo 2) with fused bilinear W-upsample (129 -> 256)
  for (int idx = tid; idx < 1200; idx += 256) {
    int c = idx / 400, r = idx % 400, iy = r / 20, ix = r % 20;
    int gy = ty0 - 2 + iy, gx = tx0 - 2 + ix;
    float v = 0.f;
    if ((unsigned)gy < 256u && (unsigned)gx < 256u) {
      float srcx = ((float)gx + 0.5f) * (129.0f / 256.0f) - 0.5f;
      float fl = floorf(srcx);
      float w = srcx - fl;
      int x0 = (int)fl, x1 = x0 + 1;
      x0 = x0 < 0 ? 0 : x0;
      x1 = x1 > 128 ? 128 : x1;
      const float* rowp = src + ((size_t)(b * 3 + c) * 256 + gy) * 129;
      v = rowp[x0] * (1.f - w) + rowp[x1] * w;
    }
    s_in[c][iy][ix] = v;
  }
  if (tid < C2) { s_sc1[tid] = s1[tid]; s_sh1[tid] = t1[tid]; }

  // conv1 A-side weights (all oc tiles; A[m=oc][k=tap])
  bf16x8 b1[NT];
#pragma unroll
  for (int nt = 0; nt < NT; ++nt)
    b1[nt] = *(const bf16x8*)&w1b[(nt * 16 + ln) * 32 + q * 8];

  // conv2 B prefetch (issued before conv1 so the pipe is warm at conv2 start)
  bf16x8 Bb[2][3 * WNT];     // rolling (C2==64)
  bf16x8 Bw[(C2 == 32) ? 9 : 1];
  if constexpr (C2 == 64) {
#pragma unroll
    for (int ky = 0; ky < 3; ++ky)
#pragma unroll
      for (int w = 0; w < 2; ++w)
        Bb[0][ky * 2 + w] =
            *(const bf16x8*)&wB[((size_t)(ky * 3) * 64 + ocb0 + w * 16 + ln) * 64 + q * 8];
  } else {
#pragma unroll
    for (int kx = 0; kx < 3; ++kx)
#pragma unroll
      for (int ky = 0; ky < 3; ++ky)
        Bw[kx * 3 + ky] =
            *(const bf16x8*)&wB[((size_t)(ky * 3 + kx) * 32 + ocb0 + ln) * 32 + q * 8];
  }

  __syncthreads();

  // BN params for conv1 writeback (oc = nt*16 + q*4 + r)
  float c1sc[NT][4], c1sh[NT][4];
#pragma unroll
  for (int nt = 0; nt < NT; ++nt)
#pragma unroll
    for (int r = 0; r < 4; ++r) {
      c1sc[nt][r] = s_sc1[nt * 16 + q * 4 + r];
      c1sh[nt][r] = s_sh1[nt * 16 + q * 4 + r];
    }

  // ---- phase 1: conv1 via MFMA (D[oc][pixel]); 18x18 halo = 324 px in 21 m-tiles ----
  const float* sp = &s_in[0][0][0];
  int koff[8];
#pragma unroll
  for (int j = 0; j < 8; ++j) {
    int k = q * 8 + j;  // k = c*9 + dy*3 + dx
    if (k < 27) {
      int c = k / 9, rr = k - c * 9, dy = rr / 3, dx = rr - dy * 3;
      koff[j] = (c * 20 + dy) * 20 + dx;
    } else koff[j] = -1;
  }
  for (int mt = wv; mt < 21; mt += 4) {
    int p = mt * 16 + ln;
    int pc = p < 324 ? p : 0;           // dummy pixel for pad lanes (cols discarded)
    int py = pc / 18, px = pc - py * 18;
    int pix = py * 20 + px;
    union { bf16x8 v; unsigned u[4]; } af;
#pragma unroll
    for (int jj = 0; jj < 4; ++jj) {
      float v0 = (koff[2 * jj] >= 0) ? sp[koff[2 * jj] + pix] : 0.f;
      float v1 = (koff[2 * jj + 1] >= 0) ? sp[koff[2 * jj + 1] + pix] : 0.f;
      af.u[jj] = (unsigned)f2bf(v0) | ((unsigned)f2bf(v1) << 16);
    }
    bool inim = false;
    if (p < 324) {
      int gy = ty0 - 1 + py, gx = tx0 - 1 + px;
      inim = ((unsigned)gy < 256u) && ((unsigned)gx < 256u);
    }
#pragma unroll
    for (int nt = 0; nt < NT; ++nt) {
      f32x4 c1 = __builtin_amdgcn_mfma_f32_16x16x32_bf16(
          b1[nt], af.v, (f32x4){0.f, 0.f, 0.f, 0.f}, 0, 0, 0);
      if (p < 324) {
        float v0 = inim ? fmaxf(fmaf(c1[0], c1sc[nt][0], c1sh[nt][0]), 0.f) : 0.f;
        float v1 = inim ? fmaxf(fmaf(c1[1], c1sc[nt][1], c1sh[nt][1]), 0.f) : 0.f;
        float v2 = inim ? fmaxf(fmaf(c1[2], c1sc[nt][2], c1sh[nt][2]), 0.f) : 0.f;
        float v3 = inim ? fmaxf(fmaf(c1[3], c1sc[nt][3], c1sh[nt][3]), 0.f) : 0.f;
        uint2 pk;
        pk.x = (unsigned)f2bf(v0) | ((unsigned)f2bf(v1) << 16);
        pk.y = (unsigned)f2bf(v2) | ((unsigned)f2bf(v3) << 16);
        *(uint2*)&s_f1[p * ST + nt * 16 + q * 4] = pk;  // 8B aligned
      }
    }
  }
  __syncthreads();

  // ---- phase 2: conv2 implicit GEMM; wave = WNT oc-tiles x 8 pixel-rows ----
  f32x4 acc[WNT][8];
#pragma unroll
  for (int w = 0; w < WNT; ++w)
#pragma unroll
    for (int i = 0; i < 8; ++i)
      acc[w][i] = (f32x4){0.f, 0.f, 0.f, 0.f};

  const int rbase = half * 8;
#pragma unroll
  for (int g = 0; g < NG; ++g) {
    const int kx = g / KS, ks = g % KS;
    if constexpr (C2 == 64) {
      if (g + 1 < NG) {
        const int nkx = (g + 1) / KS, nks = (g + 1) % KS;
#pragma unroll
        for (int ky = 0; ky < 3; ++ky)
#pragma unroll
          for (int w = 0; w < 2; ++w)
            Bb[(g + 1) & 1][ky * 2 + w] =
                *(const bf16x8*)&wB[((size_t)(ky * 3 + nkx) * 64 + ocb0 + w * 16 + ln) * 64 +
                                    nks * 32 + q * 8];
      }
    }
    bf16x8 a[10];
#pragma unroll
    for (int rr = 0; rr < 10; ++rr)
      a[rr] = *(const bf16x8*)&s_f1[((rbase + rr) * 18 + ln + kx) * ST + ks * 32 + q * 8];
#pragma unroll
    for (int ky = 0; ky < 3; ++ky)
#pragma unroll
      for (int w = 0; w < WNT; ++w) {
        bf16x8 bf;
        if constexpr (C2 == 64) bf = Bb[g & 1][ky * 2 + w];
        else bf = Bw[kx * 3 + ky];
#pragma unroll
        for (int i = 0; i < 8; ++i)
          acc[w][i] = __builtin_amdgcn_mfma_f32_16x16x32_bf16(a[i + ky], bf, acc[w][i], 0, 0, 0);
      }
  }

  // epilogue: BN+ReLU + pool partial. D: col(ln)=oc, rows=pixel cols (q*4+r).
#pragma unroll
  for (int w = 0; w < WNT; ++w) {
    const int oc = ocb0 + w * 16 + ln;
    const float sc = s2[oc], sh = t2[oc];
    float v = 0.f;
#pragma unroll
    for (int i = 0; i < 8; ++i)
#pragma unroll
      for (int r = 0; r < 4; ++r)
        v += fmaxf(fmaf(acc[w][i][r], sc, sh), 0.f);
    v += __shfl_xor(v, 16);
    v += __shfl_xor(v, 32);
    if (q == 0) atomicAdd(&pool[b * C2 + oc], v);
  }
}

// ---------------- final: radial conv branch + comb + linear/LN/relu/linear ----------------
__global__ __launch_bounds__(256) void final_mlp(
    const float* __restrict__ rsum, const float* __restrict__ rcnt,
    const float* __restrict__ rw1, const float* __restrict__ rw2,
    const float* __restrict__ sr1, const float* __restrict__ tr1,
    const float* __restrict__ sr2, const float* __restrict__ tr2,
    const float* __restrict__ mpool, const float* __restrict__ ppool,
    const float* __restrict__ as1, const float* __restrict__ as2,
    const float* __restrict__ acnt,
    const float* __restrict__ lw1, const float* __restrict__ lb1,
    const float* __restrict__ lng, const float* __restrict__ lnb,
    const float* __restrict__ lw2, const float* __restrict__ lb2,
    float* __restrict__ out) {
  int b = blockIdx.x, t = threadIdx.x;
  __shared__ float rad[3][32];
  __shared__ float rf1[32][32];
  __shared__ float rf2[32][32];
  __shared__ float rfv[32];
  __shared__ float comb[176];
  __shared__ float red[256];
  __shared__ float hrelu[256];
  __shared__ float s_mu, s_var;

  if (t < 96) {
    int c = t / 32, i = t % 32;
    float cnt = fmaxf(rcnt[i], 1.0f);
    float v = rsum[(b * 3 + c) * 32 + i] / cnt;
    rad[c][i] = fminf(fmaxf(v, 0.f), 1e6f);
  }
  __syncthreads();
  for (int idx = t; idx < 1024; idx += 256) {
    int oc = idx >> 5, i = idx & 31;
    float a = 0.f;
    for (int c = 0; c < 3; ++c)
#pragma unroll
      for (int d = 0; d < 3; ++d) {
        int ii = i + d - 1;
        if (ii >= 0 && ii < 32) a = fmaf(rad[c][ii], rw1[(oc * 3 + c) * 3 + d], a);
      }
    rf1[oc][i] = fmaxf(fmaf(a, sr1[oc], tr1[oc]), 0.f);
  }
  __syncthreads();
  for (int idx = t; idx < 1024; idx += 256) {
    int oc = idx >> 5, i = idx & 31;
    float a = 0.f;
    for (int c = 0; c < 32; ++c)
#pragma unroll
      for (int d = 0; d < 3; ++d) {
        int ii = i + d - 1;
        if (ii >= 0 && ii < 32) a = fmaf(rf1[c][ii], rw2[(oc * 32 + c) * 3 + d], a);
      }
    rf2[oc][i] = fmaxf(fmaf(a, sr2[oc], tr2[oc]), 0.f);
  }
  __syncthreads();
  if (t < 32) {
    float s = 0.f;
    for (int i = 0; i < 32; ++i) s += rf2[t][i];
    rfv[t] = s * (1.0f / 32.0f);
  }
  __syncthreads();

  if (t < 64) comb[t] = fix_nan(mpool[b * 64 + t] * (1.0f / 65536.0f), 1e4f, -1e4f);
  else if (t < 96) comb[t] = fix_nan(ppool[b * 32 + t - 64] * (1.0f / 65536.0f), 1e4f, -1e4f);
  else if (t < 128) comb[t] = fix_nan(rfv[t - 96], 1e4f, -1e4f);
  else if (t < 176) {
    int j = t - 128;
    int a = j / 6, r = j % 6, m = r / 3, c = r % 3;
    float cnt = acnt[a];
    float v = 0.f;  // empty sector -> NaN -> nan_to_num -> 0
    if (cnt > 0.f) {
      float s1v = as1[(b * 3 + c) * 8 + a], s2v = as2[(b * 3 + c) * 8 + a];
      float mean = s1v / cnt;
      if (m == 0)
        v = mean;
      else {
        float var = (s2v - cnt * mean * mean) / fmaxf(cnt - 1.f, 1.f);
        v = sqrtf(fmaxf(var, 0.f));
      }
    }
    comb[t] = fix_nan(v, 1e4f, -1e4f);
  }
  __syncthreads();
  // 4-way ILP partial sums (latency-exposed 16-block kernel)
  const float* wr = lw1 + t * 176;
  float h0 = 0.f, h1 = 0.f, h2 = 0.f, h3 = 0.f;
#pragma unroll 4
  for (int j = 0; j < 176; j += 4) {
    h0 = fmaf(comb[j], wr[j], h0);
    h1 = fmaf(comb[j + 1], wr[j + 1], h1);
    h2 = fmaf(comb[j + 2], wr[j + 2], h2);
    h3 = fmaf(comb[j + 3], wr[j + 3], h3);
  }
  float h = lb1[t] + ((h0 + h1) + (h2 + h3));
  red[t] = h;
  __syncthreads();
  for (int s = 128; s > 0; s >>= 1) {
    if (t < s) red[t] += red[t + s];
    __syncthreads();
  }
  if (t == 0) s_mu = red[0] * (1.0f / 256.0f);
  __syncthreads();
  float mu = s_mu;
  float d = h - mu;
  red[t] = d * d;
  __syncthreads();
  for (int s = 128; s > 0; s >>= 1) {
    if (t < s) red[t] += red[t + s];
    __syncthreads();
  }
  if (t == 0) s_var = red[0] * (1.0f / 256.0f);
  __syncthreads();
  float hn = d / sqrtf(s_var + 1e-5f) * lng[t] + lnb[t];
  hrelu[t] = fmaxf(hn, 0.f);
  __syncthreads();
  if (t < 128) {
    const float* w2r = lw2 + t * 256;
    float o0 = 0.f, o1 = 0.f, o2 = 0.f, o3 = 0.f;
#pragma unroll 4
    for (int j = 0; j < 256; j += 4) {
      o0 = fmaf(hrelu[j], w2r[j], o0);
      o1 = fmaf(hrelu[j + 1], w2r[j + 1], o1);
      o2 = fmaf(hrelu[j + 2], w2r[j + 2], o2);
      o3 = fmaf(hrelu[j + 3], w2r[j + 3], o3);
    }
    float o = lb2[t] + ((o0 + o1) + (o2 + o3));
    o = fminf(fmaxf(o, -100.f), 100.f);
    out[b * 128 + t] = fix_nan(o, 100.f, -100.f);
  }
}

// ---------------- host launcher ----------------
extern "C" void kernel_launch(void* const* d_in, const int* in_sizes, int n_in,
                              void* d_out, int out_size, void* d_ws, size_t ws_size,
                              hipStream_t stream) {
  const float* x    = (const float*)d_in[0];
  const float* mw1  = (const float*)d_in[1];
  const float* mb1  = (const float*)d_in[2];
  const float* mbn1 = (const float*)d_in[3];
  const float* mw2  = (const float*)d_in[4];
  const float* mb2  = (const float*)d_in[5];
  const float* mbn2 = (const float*)d_in[6];
  const float* pw1  = (const float*)d_in[7];
  const float* pb1  = (const float*)d_in[8];
  const float* pbn1 = (const float*)d_in[9];
  const float* pw2  = (const float*)d_in[10];
  const float* pb2  = (const float*)d_in[11];
  const float* pbn2 = (const float*)d_in[12];
  const float* rw1  = (const float*)d_in[13];
  const float* rb1  = (const float*)d_in[14];
  const float* rbn1 = (const float*)d_in[15];
  const float* rw2  = (const float*)d_in[16];
  const float* rb2  = (const float*)d_in[17];
  const float* rbn2 = (const float*)d_in[18];
  const float* lw1  = (const float*)d_in[19];
  const float* lb1  = (const float*)d_in[20];
  const float* lng  = (const float*)d_in[21];
  const float* lnb  = (const float*)d_in[22];
  const float* lw2  = (const float*)d_in[23];
  const float* lb2  = (const float*)d_in[24];

  float* ws = (float*)d_ws;
  float* out = (float*)d_out;

  float* fc    = ws + OFF_FC;
  float* mlog  = ws + OFF_MLOG;
  float* phb   = ws + OFF_PH;
  float* rsum  = ws + OFF_RSUM;
  float* rcnt  = ws + OFF_RCNT;
  float* as1   = ws + OFF_AS1;
  float* as2   = ws + OFF_AS2;
  float* acnt  = ws + OFF_ACNT;
  float* mpool = ws + OFF_MPOOL;
  float* ppool = ws + OFF_PPOOL;
  float* par   = ws + OFF_PAR;
  unsigned short* wbm  = (unsigned short*)(ws + OFF_WBM);
  unsigned short* wbp  = (unsigned short*)(ws + OFF_WBP);
  unsigned short* w1bm = (unsigned short*)(ws + OFF_W1BM);
  unsigned short* w1bp = (unsigned short*)(ws + OFF_W1BP);

  row_fft_prep<<<6337, 256, 0, stream>>>(x, fc, rsum,
                                         mw1, pw1, mw2, pw2, mb1, mbn1, mb2, mbn2,
                                         pb1, pbn1, pb2, pbn2, rb1, rbn1, rb2, rbn2,
                                         par, wbm, wbp, w1bm, w1bp);
  col_fft_stats<<<dim3(33, 16, 3), 256, 0, stream>>>(fc, mlog, phb, rsum, rcnt,
                                                     as1, as2, acnt);
  conv_mfma<64><<<dim3(16, 16, 16), 256, 0, stream>>>(
      mlog, w1bm, wbm, par + 0, par + 64, par + 128, par + 192, mpool);
  conv_mfma<32><<<dim3(16, 16, 16), 256, 0, stream>>>(
      phb, w1bp, wbp, par + 256, par + 288, par + 320, par + 352, ppool);
  final_mlp<<<16, 256, 0, stream>>>(rsum, rcnt, rw1, rw2, par + 384, par + 416,
                                    par + 448, par + 480, mpool, ppool, as1, as2,
                                    acnt, lw1, lb1, lng, lnb, lw2, lb2, out);
}

// Round 12
// 402.532 us; speedup vs baseline: 1.4528x; 1.0827x over previous
//
#include <hip/hip_runtime.h>
#include <math.h>

#define PI_F 3.14159274101257324f   // float(np.pi)
#define TWO_PI_256 0.02454369260617026f   // 2*pi/256
#define TWO_PI_16  0.39269908169872414f   // 2*pi/16

typedef __attribute__((ext_vector_type(8))) short bf16x8;   // 4 VGPRs
typedef __attribute__((ext_vector_type(4))) float f32x4;

// ---------------- workspace layout (float offsets) ----------------
static const size_t OFF_FC    = 0;                    // row-FFT complex out [B*C*256][129]*2
static const size_t OFF_MLOG  = 3170304;              // [B,C,256,129]  (j-major: staging-coalesced)
static const size_t OFF_PH    = 4755456;              // [B,C,256,129]
static const size_t OFF_RSUM  = 9486336;              // [B,C,32]
static const size_t OFF_RCNT  = OFF_RSUM + 1536;      // [32]
static const size_t OFF_AS1   = OFF_RCNT + 32;        // [B,C,8]
static const size_t OFF_AS2   = OFF_AS1 + 384;        // [B,C,8]
static const size_t OFF_ACNT  = OFF_AS2 + 384;        // [8]
static const size_t OFF_MPOOL = OFF_ACNT + 8;         // [B,64]
static const size_t OFF_PPOOL = OFF_MPOOL + 1024;     // [B,32]
static const size_t OFF_RF    = OFF_PPOOL + 512;      // (unused)
static const size_t OFF_PAR   = OFF_RF + 512;         // 512 folded BN params
static const size_t OFF_WBM   = OFF_PAR + 512;        // mag conv2 w [9][64][64] bf16
static const size_t OFF_WBP   = OFF_WBM + 18432;      // ph conv2 w [9][32][32] bf16
static const size_t OFF_W1BM  = OFF_WBP + 4608;       // mag conv1 w [64][32] bf16
static const size_t OFF_W1BP  = OFF_W1BM + 1024;      // ph conv1 w [32][32] bf16
// param sub-offsets: sm1 0, tm1 64, sm2 128, tm2 192, sp1 256, tp1 288, sp2 320, tp2 352,
//                    sr1 384, tr1 416, sr2 448, tr2 480

__device__ __forceinline__ float fix_nan(float v, float pinf, float ninf) {
  if (isnan(v)) return 0.f;
  if (isinf(v)) return v > 0.f ? pinf : ninf;
  return v;
}

__device__ __forceinline__ unsigned short f2bf(float f) {
  unsigned u = __float_as_uint(f);
  unsigned r = (u + 0x7FFFu + ((u >> 16) & 1u)) >> 16;   // RNE (finite values only)
  return (unsigned short)r;
}

__device__ __forceinline__ void fold_bn(const float* bn, int C, int c, float cb,
                                        float* s, float* t) {
  float g = bn[c], b = bn[C + c], m = bn[2 * C + c], v = bn[3 * C + c];
  float sc = g / sqrtf(v + 1e-5f);
  *s = sc;
  *t = b + (cb - m) * sc;
}

// ---------------- row rFFT (radix-16, 2 rows/block) + fused prep + zeroing ----------------
__global__ __launch_bounds__(256) void row_fft_prep(
    const float* __restrict__ x, float* __restrict__ Fc, float* __restrict__ zbuf,
    const float* __restrict__ mw1, const float* __restrict__ pw1,
    const float* __restrict__ mw2, const float* __restrict__ pw2,
    const float* __restrict__ mb1, const float* __restrict__ mbn1,
    const float* __restrict__ mb2, const float* __restrict__ mbn2,
    const float* __restrict__ pb1, const float* __restrict__ pbn1,
    const float* __restrict__ pb2, const float* __restrict__ pbn2,
    const float* __restrict__ rb1, const float* __restrict__ rbn1,
    const float* __restrict__ rb2, const float* __restrict__ rbn2,
    float* __restrict__ par, unsigned short* __restrict__ wbm,
    unsigned short* __restrict__ wbp, unsigned short* __restrict__ w1bm,
    unsigned short* __restrict__ w1bp) {
  const int blk = blockIdx.x;
  const int tid = threadIdx.x;
  if (blk >= 6144) {
    int idx = (blk - 6144) * 256 + tid;
    if (idx < 36864) {
      int pos = idx / 4096, rem = idx % 4096;
      int oc = rem >> 6, ci = rem & 63;
      wbm[idx] = f2bf(mw2[(oc * 64 + ci) * 9 + pos]);
    } else if (idx < 46080) {
      int i = idx - 36864;
      int pos = i / 1024, rem = i % 1024;
      int oc = rem >> 5, ci = rem & 31;
      wbp[i] = f2bf(pw2[(oc * 32 + ci) * 9 + pos]);
    } else if (idx < 46336) {
      int i = idx - 46080;  // 0..255
      float s, t;
      if (i < 64)       { fold_bn(mbn1, 64, i, mb1[i], &s, &t);          par[i] = s;       par[64 + i] = t; }
      else if (i < 128) { int c = i - 64;  fold_bn(mbn2, 64, c, mb2[c], &s, &t); par[128 + c] = s; par[192 + c] = t; }
      else if (i < 160) { int c = i - 128; fold_bn(pbn1, 32, c, pb1[c], &s, &t); par[256 + c] = s; par[288 + c] = t; }
      else if (i < 192) { int c = i - 160; fold_bn(pbn2, 32, c, pb2[c], &s, &t); par[320 + c] = s; par[352 + c] = t; }
      else if (i < 224) { int c = i - 192; fold_bn(rbn1, 32, c, rb1[c], &s, &t); par[384 + c] = s; par[416 + c] = t; }
      else              { int c = i - 224; fold_bn(rbn2, 32, c, rb2[c], &s, &t); par[448 + c] = s; par[480 + c] = t; }
    } else if (idx < 48384) {
      int i = idx - 46336;                 // conv1 mag w [oc][k], k=c*9+dy*3+dx, pad->0
      int oc = i >> 5, k = i & 31;
      w1bm[i] = (k < 27) ? f2bf(mw1[oc * 27 + k]) : (unsigned short)0;
    } else if (idx < 49408) {
      int i = idx - 48384;
      int oc = i >> 5, k = i & 31;
      w1bp[i] = (k < 27) ? f2bf(pw1[oc * 27 + k]) : (unsigned short)0;
    }
    return;
  }
  if (blk == 0) {
    for (int i = tid; i < 3880; i += 256) zbuf[i] = 0.f;   // rsum..ppool accumulators
  }
  __shared__ float xr[2][256];
  __shared__ float2 sS[2][256];
  for (int i = tid; i < 512; i += 256) {
    int rw = i >> 8, w = i & 255;
    float v = x[((size_t)blk * 2 + rw) * 256 + w];
    xr[rw][w] = fminf(fmaxf(v, -10.f), 10.f);
  }
  __syncthreads();
  // stage 1: both rows with shared twiddle rotation (per-row op order unchanged)
  {
    int b16 = tid >> 4, m = tid & 15;
    float sW, cW;
    sincosf(TWO_PI_16 * (float)m, &sW, &cW);   // W = e^{-i 2pi m/16}
    float sr0 = 0.f, si0 = 0.f, sr1 = 0.f, si1 = 0.f, wr = 1.f, wi = 0.f;
#pragma unroll
    for (int a = 0; a < 16; ++a) {
      float x0 = xr[0][a * 16 + b16];
      float x1 = xr[1][a * 16 + b16];
      sr0 = fmaf(x0, wr, sr0);
      si0 = fmaf(x0, wi, si0);
      sr1 = fmaf(x1, wr, sr1);
      si1 = fmaf(x1, wi, si1);
      float nr = wr * cW + wi * sW;
      float ni = wi * cW - wr * sW;
      wr = nr; wi = ni;
    }
    sS[0][b16 * 16 + m] = make_float2(sr0, si0);
    sS[1][b16 * 16 + m] = make_float2(sr1, si1);
  }
  __syncthreads();
  // stage 2: combine with W256^{kb}, both rows per thread
  if (tid < 129) {
    int m2 = tid & 15;
    float sK, cK;
    sincosf(TWO_PI_256 * (float)tid, &sK, &cK);
    float fr0 = 0.f, fi0 = 0.f, fr1 = 0.f, fi1 = 0.f, wr = 1.f, wi = 0.f;
#pragma unroll
    for (int bb = 0; bb < 16; ++bb) {
      float2 s0 = sS[0][bb * 16 + m2];
      float2 s1 = sS[1][bb * 16 + m2];
      fr0 = fmaf(s0.x, wr, fr0); fr0 = fmaf(-s0.y, wi, fr0);
      fi0 = fmaf(s0.x, wi, fi0); fi0 = fmaf(s0.y, wr, fi0);
      fr1 = fmaf(s1.x, wr, fr1); fr1 = fmaf(-s1.y, wi, fr1);
      fi1 = fmaf(s1.x, wi, fi1); fi1 = fmaf(s1.y, wr, fi1);
      float nr = wr * cK + wi * sK;
      float ni = wi * cK - wr * sK;
      wr = nr; wi = ni;
    }
    float2* o = (float2*)Fc;
    o[((size_t)blk * 2 + 0) * 129 + tid] = make_float2(fr0, fi0);
    o[((size_t)blk * 2 + 1) * 129 + tid] = make_float2(fr1, fi1);
  }
}

// ---------------- column DFT (radix-16, 4 k-columns/block, coalesced) + stats ----------------
__global__ __launch_bounds__(256) void col_fft_stats(
    const float* __restrict__ Fc, float* __restrict__ mlog, float* __restrict__ ph,
    float* __restrict__ rsum, float* __restrict__ rcnt, float* __restrict__ as1,
    float* __restrict__ as2, float* __restrict__ acnt) {
  const int kg = blockIdx.x;          // 0..32 (k = kg*4+kk; kg==32 -> only k=128)
  const int b  = blockIdx.y;          // 0..15
  const int c  = blockIdx.z;          // 0..2
  const int bc = b * 3 + c;
  const int tid = threadIdx.x;
  const int cp = tid >> 7;            // 2 histogram copies
  const int k0 = kg * 4;
  __shared__ float2 colt[4][256];     // [kk][y]
  __shared__ float2 sSt[4][256];      // [kk][b16*16+m]
  __shared__ float l_rs[2][32];
  __shared__ float l_rc[32];
  __shared__ float l_s1[2][8], l_s2[2][8];
  __shared__ float l_ac[8];
  if (tid < 64) l_rs[tid >> 5][tid & 31] = 0.f;
  if (tid < 32) l_rc[tid] = 0.f;
  if (tid < 16) { l_s1[tid >> 3][tid & 7] = 0.f; l_s2[tid >> 3][tid & 7] = 0.f; }
  if (tid < 8) l_ac[tid] = 0.f;
  const float2* fc = (const float2*)Fc;
  for (int idx = tid; idx < 1024; idx += 256) {
    int y = idx >> 2, kk = idx & 3;
    int k = k0 + kk;
    k = k > 128 ? 128 : k;            // clamp (kg==32 dups; output-guarded)
    colt[kk][y] = fc[((size_t)(bc * 256) + y) * 129 + k];
  }
  __syncthreads();
  // stage 1 (complex input), 4 columns with shared rotation
  {
    int b16 = tid >> 4, m = tid & 15;
    float sW, cW;
    sincosf(TWO_PI_16 * (float)m, &sW, &cW);
    float sr[4] = {0.f, 0.f, 0.f, 0.f}, si[4] = {0.f, 0.f, 0.f, 0.f};
    float wr = 1.f, wi = 0.f;
#pragma unroll
    for (int a = 0; a < 16; ++a) {
#pragma unroll
      for (int kk = 0; kk < 4; ++kk) {
        float2 v = colt[kk][a * 16 + b16];
        sr[kk] = fmaf(v.x, wr, sr[kk]); sr[kk] = fmaf(-v.y, wi, sr[kk]);
        si[kk] = fmaf(v.x, wi, si[kk]); si[kk] = fmaf(v.y, wr, si[kk]);
      }
      float nr = wr * cW + wi * sW;
      float ni = wi * cW - wr * sW;
      wr = nr; wi = ni;
    }
#pragma unroll
    for (int kk = 0; kk < 4; ++kk)
      sSt[kk][b16 * 16 + m] = make_float2(sr[kk], si[kk]);
  }
  __syncthreads();
  const int j = tid;
  float sK, cK;
  sincosf(TWO_PI_256 * (float)j, &sK, &cK);
  float gr[4] = {0.f, 0.f, 0.f, 0.f}, gi[4] = {0.f, 0.f, 0.f, 0.f};
  {
    const int m2 = j & 15;
    float wr = 1.f, wi = 0.f;
#pragma unroll
    for (int bb = 0; bb < 16; ++bb) {
#pragma unroll
      for (int kk = 0; kk < 4; ++kk) {
        float2 s = sSt[kk][bb * 16 + m2];
        gr[kk] = fmaf(s.x, wr, gr[kk]); gr[kk] = fmaf(-s.y, wi, gr[kk]);
        gi[kk] = fmaf(s.x, wi, gi[kk]); gi[kk] = fmaf(s.y, wr, gi[kk]);
      }
      float nr = wr * cK + wi * sK;
      float ni = wi * cK - wr * sK;
      wr = nr; wi = ni;
    }
  }
  // outputs + bins per kk (bit-exact fp32 replication of reference index math)
  float fy = (float)(j < 128 ? j : j - 256) * (1.0f / 256.0f);
  const float denom = sqrtf(0.5f) + 1e-8f;
#pragma unroll
  for (int kk = 0; kk < 4; ++kk) {
    int k = k0 + kk;
    if (k > 128) break;
    float fx = (float)k * (1.0f / 256.0f);
    float rad = sqrtf(fx * fx + fy * fy);
    int rb = (int)((rad / denom) * 31.0f);
    rb = rb < 0 ? 0 : (rb > 31 ? 31 : rb);
    float ang = atan2f(fy, fx + 1e-8f);
    int ab = (int)((ang + PI_F) / (2.0f * PI_F) * 8.0f);
    ab = ab < 0 ? 0 : (ab > 7 ? 7 : ab);
    float mag = sqrtf(gr[kk] * gr[kk] + gi[kk] * gi[kk]);
    mag = fminf(fmaxf(mag, 1e-8f), 1e6f);
    float ml = fminf(fmaxf(log1pf(mag), -20.f), 20.f);
    float p = fminf(fmaxf(atan2f(gi[kk], gr[kk]) / PI_F, -1.f), 1.f);
    size_t oidx = ((size_t)(bc * 256) + j) * 129 + k;   // j-major
    mlog[oidx] = ml;
    ph[oidx] = p;
    atomicAdd(&l_rs[cp][rb], mag);
    atomicAdd(&l_s1[cp][ab], mag);
    atomicAdd(&l_s2[cp][ab], mag * mag);
    if (b == 0 && c == 0) {
      atomicAdd(&l_rc[rb], 1.0f);
      atomicAdd(&l_ac[ab], 1.0f);
    }
  }
  __syncthreads();
  if (tid < 32) {
    atomicAdd(&rsum[bc * 32 + tid], l_rs[0][tid] + l_rs[1][tid]);
  } else if (tid < 40) {
    int a = tid - 32;
    atomicAdd(&as1[bc * 8 + a], l_s1[0][a] + l_s1[1][a]);
    atomicAdd(&as2[bc * 8 + a], l_s2[0][a] + l_s2[1][a]);
  }
  if (b == 0 && c == 0) {
    if (tid < 32) atomicAdd(&rcnt[tid], l_rc[tid]);
    else if (tid < 40) atomicAdd(&acnt[tid - 32], l_ac[tid - 32]);
  }
}

// ---------------- fused upsample -> conv1(MFMA) -> conv2(MFMA) -> pool ----------------
// Round-10 body VERBATIM (152.9 us, FETCH 16.6 MB, VGPR 72, no spill), now shared
// by both branches in ONE dispatch (z<16: mag C2=64; z>=16: phase C2=32) so light
// phase blocks pack under heavy mag blocks' latency. Spill tripwire: WRITE_SIZE
// must stay ~MB (rounds 7-9: K-split+prefetch combo spilled -> 1.1 GB; this body
// does NOT use that combo).
template <int C2>
__device__ __forceinline__ void conv_body(
    const float* __restrict__ src,           // [B,3,256,129] spectral plane (j-major)
    const unsigned short* __restrict__ w1b,  // [C2][32] bf16 conv1 weights
    const unsigned short* __restrict__ wB,   // [9][C2][C2] bf16 conv2 [pos][oc][ci]
    const float* __restrict__ s1, const float* __restrict__ t1,
    const float* __restrict__ s2, const float* __restrict__ t2,
    float* __restrict__ pool, int b, int tx0, int ty0, int tid,
    float (&s_in)[3][20][20], float* s_sc1, float* s_sh1, unsigned short* s_f1) {
  constexpr int ST = C2 + 8;                 // f1 row stride (16B-aligned rows)
  constexpr int NT = C2 / 16;                // total oc tiles
  constexpr int WNT = (C2 == 64) ? 2 : 1;    // oc tiles per wave
  constexpr int KS = C2 / 32;                // conv2 K steps per kx
  constexpr int NG = 3 * KS;                 // (kx,ks) granules

  const int lane = tid & 63, wv = tid >> 6;
  const int ln = lane & 15, q = lane >> 4;
  const int ntg = wv & 1, half = wv >> 1;
  const int ocb0 = ntg * WNT * 16;

  // stage input tile (halo 2) with fused bilinear W-upsample (129 -> 256)
  for (int idx = tid; idx < 1200; idx += 256) {
    int c = idx / 400, r = idx % 400, iy = r / 20, ix = r % 20;
    int gy = ty0 - 2 + iy, gx = tx0 - 2 + ix;
    float v = 0.f;
    if ((unsigned)gy < 256u && (unsigned)gx < 256u) {
      float srcx = ((float)gx + 0.5f) * (129.0f / 256.0f) - 0.5f;
      float fl = floorf(srcx);
      float w = srcx - fl;
      int x0 = (int)fl, x1 = x0 + 1;
      x0 = x0 < 0 ? 0 : x0;
      x1 = x1 > 128 ? 128 : x1;
      const float* rowp = src + ((size_t)(b * 3 + c) * 256 + gy) * 129;
      v = rowp[x0] * (1.f - w) + rowp[x1] * w;
    }
    s_in[c][iy][ix] = v;
  }
  if (tid < C2) { s_sc1[tid] = s1[tid]; s_sh1[tid] = t1[tid]; }

  // conv1 A-side weights (all oc tiles; A[m=oc][k=tap])
  bf16x8 b1[NT];
#pragma unroll
  for (int nt = 0; nt < NT; ++nt)
    b1[nt] = *(const bf16x8*)&w1b[(nt * 16 + ln) * 32 + q * 8];

  // conv2 B prefetch (issued before conv1 so the pipe is warm at conv2 start)
  bf16x8 Bb[2][3 * WNT];     // rolling (C2==64)
  bf16x8 Bw[(C2 == 32) ? 9 : 1];
  if constexpr (C2 == 64) {
#pragma unroll
    for (int ky = 0; ky < 3; ++ky)
#pragma unroll
      for (int w = 0; w < 2; ++w)
        Bb[0][ky * 2 + w] =
            *(const bf16x8*)&wB[((size_t)(ky * 3) * 64 + ocb0 + w * 16 + ln) * 64 + q * 8];
  } else {
#pragma unroll
    for (int kx = 0; kx < 3; ++kx)
#pragma unroll
      for (int ky = 0; ky < 3; ++ky)
        Bw[kx * 3 + ky] =
            *(const bf16x8*)&wB[((size_t)(ky * 3 + kx) * 32 + ocb0 + ln) * 32 + q * 8];
  }

  __syncthreads();

  // BN params for conv1 writeback (oc = nt*16 + q*4 + r)
  float c1sc[NT][4], c1sh[NT][4];
#pragma unroll
  for (int nt = 0; nt < NT; ++nt)
#pragma unroll
    for (int r = 0; r < 4; ++r) {
      c1sc[nt][r] = s_sc1[nt * 16 + q * 4 + r];
      c1sh[nt][r] = s_sh1[nt * 16 + q * 4 + r];
    }

  // ---- phase 1: conv1 via MFMA (D[oc][pixel]); 18x18 halo = 324 px in 21 m-tiles ----
  const float* sp = &s_in[0][0][0];
  int koff[8];
#pragma unroll
  for (int j = 0; j < 8; ++j) {
    int k = q * 8 + j;  // k = c*9 + dy*3 + dx
    if (k < 27) {
      int c = k / 9, rr = k - c * 9, dy = rr / 3, dx = rr - dy * 3;
      koff[j] = (c * 20 + dy) * 20 + dx;
    } else koff[j] = -1;
  }
  for (int mt = wv; mt < 21; mt += 4) {
    int p = mt * 16 + ln;
    int pc = p < 324 ? p : 0;           // dummy pixel for pad lanes (cols discarded)
    int py = pc / 18, px = pc - py * 18;
    int pix = py * 20 + px;
    union { bf16x8 v; unsigned u[4]; } af;
#pragma unroll
    for (int jj = 0; jj < 4; ++jj) {
      float v0 = (koff[2 * jj] >= 0) ? sp[koff[2 * jj] + pix] : 0.f;
      float v1 = (koff[2 * jj + 1] >= 0) ? sp[koff[2 * jj + 1] + pix] : 0.f;
      af.u[jj] = (unsigned)f2bf(v0) | ((unsigned)f2bf(v1) << 16);
    }
    bool inim = false;
    if (p < 324) {
      int gy = ty0 - 1 + py, gx = tx0 - 1 + px;
      inim = ((unsigned)gy < 256u) && ((unsigned)gx < 256u);
    }
#pragma unroll
    for (int nt = 0; nt < NT; ++nt) {
      f32x4 c1 = __builtin_amdgcn_mfma_f32_16x16x32_bf16(
          b1[nt], af.v, (f32x4){0.f, 0.f, 0.f, 0.f}, 0, 0, 0);
      if (p < 324) {
        float v0 = inim ? fmaxf(fmaf(c1[0], c1sc[nt][0], c1sh[nt][0]), 0.f) : 0.f;
        float v1 = inim ? fmaxf(fmaf(c1[1], c1sc[nt][1], c1sh[nt][1]), 0.f) : 0.f;
        float v2 = inim ? fmaxf(fmaf(c1[2], c1sc[nt][2], c1sh[nt][2]), 0.f) : 0.f;
        float v3 = inim ? fmaxf(fmaf(c1[3], c1sc[nt][3], c1sh[nt][3]), 0.f) : 0.f;
        uint2 pk;
        pk.x = (unsigned)f2bf(v0) | ((unsigned)f2bf(v1) << 16);
        pk.y = (unsigned)f2bf(v2) | ((unsigned)f2bf(v3) << 16);
        *(uint2*)&s_f1[p * ST + nt * 16 + q * 4] = pk;  // 8B aligned
      }
    }
  }
  __syncthreads();

  // ---- phase 2: conv2 implicit GEMM; wave = WNT oc-tiles x 8 pixel-rows ----
  f32x4 acc[WNT][8];
#pragma unroll
  for (int w = 0; w < WNT; ++w)
#pragma unroll
    for (int i = 0; i < 8; ++i)
      acc[w][i] = (f32x4){0.f, 0.f, 0.f, 0.f};

  const int rbase = half * 8;
#pragma unroll
  for (int g = 0; g < NG; ++g) {
    const int kx = g / KS, ks = g % KS;
    if constexpr (C2 == 64) {
      if (g + 1 < NG) {
        const int nkx = (g + 1) / KS, nks = (g + 1) % KS;
#pragma unroll
        for (int ky = 0; ky < 3; ++ky)
#pragma unroll
          for (int w = 0; w < 2; ++w)
            Bb[(g + 1) & 1][ky * 2 + w] =
                *(const bf16x8*)&wB[((size_t)(ky * 3 + nkx) * 64 + ocb0 + w * 16 + ln) * 64 +
                                    nks * 32 + q * 8];
      }
    }
    bf16x8 a[10];
#pragma unroll
    for (int rr = 0; rr < 10; ++rr)
      a[rr] = *(const bf16x8*)&s_f1[((rbase + rr) * 18 + ln + kx) * ST + ks * 32 + q * 8];
#pragma unroll
    for (int ky = 0; ky < 3; ++ky)
#pragma unroll
      for (int w = 0; w < WNT; ++w) {
        bf16x8 bf;
        if constexpr (C2 == 64) bf = Bb[g & 1][ky * 2 + w];
        else bf = Bw[kx * 3 + ky];
#pragma unroll
        for (int i = 0; i < 8; ++i)
          acc[w][i] = __builtin_amdgcn_mfma_f32_16x16x32_bf16(a[i + ky], bf, acc[w][i], 0, 0, 0);
      }
  }

  // epilogue: BN+ReLU + pool partial. D: col(ln)=oc, rows=pixel cols (q*4+r).
#pragma unroll
  for (int w = 0; w < WNT; ++w) {
    const int oc = ocb0 + w * 16 + ln;
    const float sc = s2[oc], sh = t2[oc];
    float v = 0.f;
#pragma unroll
    for (int i = 0; i < 8; ++i)
#pragma unroll
      for (int r = 0; r < 4; ++r)
        v += fmaxf(fmaf(acc[w][i][r], sc, sh), 0.f);
    v += __shfl_xor(v, 16);
    v += __shfl_xor(v, 32);
    if (q == 0) atomicAdd(&pool[b * C2 + oc], v);
  }
}

__global__ __launch_bounds__(256, 2) void conv_fused(
    const float* __restrict__ msrc, const float* __restrict__ psrc,
    const unsigned short* __restrict__ w1bm, const unsigned short* __restrict__ w1bp,
    const unsigned short* __restrict__ wbm, const unsigned short* __restrict__ wbp,
    const float* __restrict__ par, float* __restrict__ mpool, float* __restrict__ ppool) {
  __shared__ float s_in[3][20][20];
  __shared__ float s_sc1[64], s_sh1[64];
  __shared__ __align__(16) unsigned short s_f1[324 * 72];   // max(ST) = 72
  const int tid = threadIdx.x;
  const int tx0 = blockIdx.x * 16, ty0 = blockIdx.y * 16;
  const int z = blockIdx.z;
  if (z < 16)   // heavy mag blocks dispatch first (z-major order), light phase tail
    conv_body<64>(msrc, w1bm, wbm, par + 0, par + 64, par + 128, par + 192,
                  mpool, z, tx0, ty0, tid, s_in, s_sc1, s_sh1, s_f1);
  else
    conv_body<32>(psrc, w1bp, wbp, par + 256, par + 288, par + 320, par + 352,
                  ppool, z - 16, tx0, ty0, tid, s_in, s_sc1, s_sh1, s_f1);
}

// ---------------- final: radial conv branch + comb + linear/LN/relu/linear ----------------
__global__ __launch_bounds__(256) void final_mlp(
    const float* __restrict__ rsum, const float* __restrict__ rcnt,
    const float* __restrict__ rw1, const float* __restrict__ rw2,
    const float* __restrict__ sr1, const float* __restrict__ tr1,
    const float* __restrict__ sr2, const float* __restrict__ tr2,
    const float* __restrict__ mpool, const float* __restrict__ ppool,
    const float* __restrict__ as1, const float* __restrict__ as2,
    const float* __restrict__ acnt,
    const float* __restrict__ lw1, const float* __restrict__ lb1,
    const float* __restrict__ lng, const float* __restrict__ lnb,
    const float* __restrict__ lw2, const float* __restrict__ lb2,
    float* __restrict__ out) {
  int b = blockIdx.x, t = threadIdx.x;
  __shared__ float rad[3][32];
  __shared__ float rf1[32][32];
  __shared__ float rf2[32][32];
  __shared__ float rfv[32];
  __shared__ float comb[176];
  __shared__ float red[256];
  __shared__ float hrelu[256];
  __shared__ float s_mu, s_var;

  if (t < 96) {
    int c = t / 32, i = t % 32;
    float cnt = fmaxf(rcnt[i], 1.0f);
    float v = rsum[(b * 3 + c) * 32 + i] / cnt;
    rad[c][i] = fminf(fmaxf(v, 0.f), 1e6f);
  }
  __syncthreads();
  for (int idx = t; idx < 1024; idx += 256) {
    int oc = idx >> 5, i = idx & 31;
    float a = 0.f;
    for (int c = 0; c < 3; ++c)
#pragma unroll
      for (int d = 0; d < 3; ++d) {
        int ii = i + d - 1;
        if (ii >= 0 && ii < 32) a = fmaf(rad[c][ii], rw1[(oc * 3 + c) * 3 + d], a);
      }
    rf1[oc][i] = fmaxf(fmaf(a, sr1[oc], tr1[oc]), 0.f);
  }
  __syncthreads();
  for (int idx = t; idx < 1024; idx += 256) {
    int oc = idx >> 5, i = idx & 31;
    float a = 0.f;
    for (int c = 0; c < 32; ++c)
#pragma unroll
      for (int d = 0; d < 3; ++d) {
        int ii = i + d - 1;
        if (ii >= 0 && ii < 32) a = fmaf(rf1[c][ii], rw2[(oc * 32 + c) * 3 + d], a);
      }
    rf2[oc][i] = fmaxf(fmaf(a, sr2[oc], tr2[oc]), 0.f);
  }
  __syncthreads();
  if (t < 32) {
    float s = 0.f;
    for (int i = 0; i < 32; ++i) s += rf2[t][i];
    rfv[t] = s * (1.0f / 32.0f);
  }
  __syncthreads();

  if (t < 64) comb[t] = fix_nan(mpool[b * 64 + t] * (1.0f / 65536.0f), 1e4f, -1e4f);
  else if (t < 96) comb[t] = fix_nan(ppool[b * 32 + t - 64] * (1.0f / 65536.0f), 1e4f, -1e4f);
  else if (t < 128) comb[t] = fix_nan(rfv[t - 96], 1e4f, -1e4f);
  else if (t < 176) {
    int j = t - 128;
    int a = j / 6, r = j % 6, m = r / 3, c = r % 3;
    float cnt = acnt[a];
    float v = 0.f;  // empty sector -> NaN -> nan_to_num -> 0
    if (cnt > 0.f) {
      float s1v = as1[(b * 3 + c) * 8 + a], s2v = as2[(b * 3 + c) * 8 + a];
      float mean = s1v / cnt;
      if (m == 0)
        v = mean;
      else {
        float var = (s2v - cnt * mean * mean) / fmaxf(cnt - 1.f, 1.f);
        v = sqrtf(fmaxf(var, 0.f));
      }
    }
    comb[t] = fix_nan(v, 1e4f, -1e4f);
  }
  __syncthreads();
  // 4-way ILP partial sums (latency-exposed 16-block kernel)
  const float* wr = lw1 + t * 176;
  float h0 = 0.f, h1 = 0.f, h2 = 0.f, h3 = 0.f;
#pragma unroll 4
  for (int j = 0; j < 176; j += 4) {
    h0 = fmaf(comb[j], wr[j], h0);
    h1 = fmaf(comb[j + 1], wr[j + 1], h1);
    h2 = fmaf(comb[j + 2], wr[j + 2], h2);
    h3 = fmaf(comb[j + 3], wr[j + 3], h3);
  }
  float h = lb1[t] + ((h0 + h1) + (h2 + h3));
  red[t] = h;
  __syncthreads();
  for (int s = 128; s > 0; s >>= 1) {
    if (t < s) red[t] += red[t + s];
    __syncthreads();
  }
  if (t == 0) s_mu = red[0] * (1.0f / 256.0f);
  __syncthreads();
  float mu = s_mu;
  float d = h - mu;
  red[t] = d * d;
  __syncthreads();
  for (int s = 128; s > 0; s >>= 1) {
    if (t < s) red[t] += red[t + s];
    __syncthreads();
  }
  if (t == 0) s_var = red[0] * (1.0f / 256.0f);
  __syncthreads();
  float hn = d / sqrtf(s_var + 1e-5f) * lng[t] + lnb[t];
  hrelu[t] = fmaxf(hn, 0.f);
  __syncthreads();
  if (t < 128) {
    const float* w2r = lw2 + t * 256;
    float o0 = 0.f, o1 = 0.f, o2 = 0.f, o3 = 0.f;
#pragma unroll 4
    for (int j = 0; j < 256; j += 4) {
      o0 = fmaf(hrelu[j], w2r[j], o0);
      o1 = fmaf(hrelu[j + 1], w2r[j + 1], o1);
      o2 = fmaf(hrelu[j + 2], w2r[j + 2], o2);
      o3 = fmaf(hrelu[j + 3], w2r[j + 3], o3);
    }
    float o = lb2[t] + ((o0 + o1) + (o2 + o3));
    o = fminf(fmaxf(o, -100.f), 100.f);
    out[b * 128 + t] = fix_nan(o, 100.f, -100.f);
  }
}

// ---------------- host launcher ----------------
extern "C" void kernel_launch(void* const* d_in, const int* in_sizes, int n_in,
                              void* d_out, int out_size, void* d_ws, size_t ws_size,
                              hipStream_t stream) {
  const float* x    = (const float*)d_in[0];
  const float* mw1  = (const float*)d_in[1];
  const float* mb1  = (const float*)d_in[2];
  const float* mbn1 = (const float*)d_in[3];
  const float* mw2  = (const float*)d_in[4];
  const float* mb2  = (const float*)d_in[5];
  const float* mbn2 = (const float*)d_in[6];
  const float* pw1  = (const float*)d_in[7];
  const float* pb1  = (const float*)d_in[8];
  const float* pbn1 = (const float*)d_in[9];
  const float* pw2  = (const float*)d_in[10];
  const float* pb2  = (const float*)d_in[11];
  const float* pbn2 = (const float*)d_in[12];
  const float* rw1  = (const float*)d_in[13];
  const float* rb1  = (const float*)d_in[14];
  const float* rbn1 = (const float*)d_in[15];
  const float* rw2  = (const float*)d_in[16];
  const float* rb2  = (const float*)d_in[17];
  const float* rbn2 = (const float*)d_in[18];
  const float* lw1  = (const float*)d_in[19];
  const float* lb1  = (const float*)d_in[20];
  const float* lng  = (const float*)d_in[21];
  const float* lnb  = (const float*)d_in[22];
  const float* lw2  = (const float*)d_in[23];
  const float* lb2  = (const float*)d_in[24];

  float* ws = (float*)d_ws;
  float* out = (float*)d_out;

  float* fc    = ws + OFF_FC;
  float* mlog  = ws + OFF_MLOG;
  float* phb   = ws + OFF_PH;
  float* rsum  = ws + OFF_RSUM;
  float* rcnt  = ws + OFF_RCNT;
  float* as1   = ws + OFF_AS1;
  float* as2   = ws + OFF_AS2;
  float* acnt  = ws + OFF_ACNT;
  float* mpool = ws + OFF_MPOOL;
  float* ppool = ws + OFF_PPOOL;
  float* par   = ws + OFF_PAR;
  unsigned short* wbm  = (unsigned short*)(ws + OFF_WBM);
  unsigned short* wbp  = (unsigned short*)(ws + OFF_WBP);
  unsigned short* w1bm = (unsigned short*)(ws + OFF_W1BM);
  unsigned short* w1bp = (unsigned short*)(ws + OFF_W1BP);

  row_fft_prep<<<6337, 256, 0, stream>>>(x, fc, rsum,
                                         mw1, pw1, mw2, pw2, mb1, mbn1, mb2, mbn2,
                                         pb1, pbn1, pb2, pbn2, rb1, rbn1, rb2, rbn2,
                                         par, wbm, wbp, w1bm, w1bp);
  col_fft_stats<<<dim3(33, 16, 3), 256, 0, stream>>>(fc, mlog, phb, rsum, rcnt,
                                                     as1, as2, acnt);
  conv_fused<<<dim3(16, 16, 32), 256, 0, stream>>>(mlog, phb, w1bm, w1bp, wbm, wbp,
                                                   par, mpool, ppool);
  final_mlp<<<16, 256, 0, stream>>>(rsum, rcnt, rw1, rw2, par + 384, par + 416,
                                    par + 448, par + 480, mpool, ppool, as1, as2,
                                    acnt, lw1, lb1, lng, lnb, lw2, lb2, out);
}